// Round 1
// baseline (2263.663 us; speedup 1.0000x reference)
//
#include <hip/hip_runtime.h>
#include <hip/hip_bf16.h>
#include <math.h>

#define N_NODES 50000
#define N_EDGES 800000
#define IN_DIM 128
#define HID_DIM 256
#define OUT_DIM 64

// ---------------- degree / norm ----------------
__global__ void deg_kernel(const int* __restrict__ dst, float* __restrict__ deg, int E) {
    int e = blockIdx.x * blockDim.x + threadIdx.x;
    if (e < E) atomicAdd(&deg[dst[e]], 1.0f);
}

__global__ void dis_kernel(float* __restrict__ deg, int n) {
    int i = blockIdx.x * blockDim.x + threadIdx.x;
    if (i < n) deg[i] = rsqrtf(deg[i] + 1.0f);   // +1 for self-loop
}

// ---------------- layer-1 scatter (aggregate-first, 128 dims, 32 lanes/edge) ----------------
__global__ void scatter1_kernel(const float* __restrict__ x, const int* __restrict__ src,
                                const int* __restrict__ dst, const float* __restrict__ dis,
                                float* __restrict__ aggx, int E) {
    int lane = threadIdx.x & 31;
    int e = blockIdx.x * (blockDim.x >> 5) + (threadIdx.x >> 5);
    if (e >= E) return;
    int s = src[e], d = dst[e];
    float norm = dis[s] * dis[d];
    float4 v = ((const float4*)(x + (size_t)s * IN_DIM))[lane];
    float* o = aggx + (size_t)d * IN_DIM + lane * 4;
    atomicAdd(o + 0, v.x * norm);
    atomicAdd(o + 1, v.y * norm);
    atomicAdd(o + 2, v.z * norm);
    atomicAdd(o + 3, v.w * norm);
}

// self-loop contribution, non-atomic (runs after scatter1 kernel completes)
__global__ void selfloop1_kernel(const float* __restrict__ x, const float* __restrict__ dis,
                                 float* __restrict__ aggx, int n) {
    int idx = blockIdx.x * blockDim.x + threadIdx.x;
    int i = idx >> 5, lane = idx & 31;
    if (i >= n) return;
    float nm = dis[i] * dis[i];
    float4 v = ((const float4*)(x + (size_t)i * IN_DIM))[lane];
    float4* o = (float4*)(aggx + (size_t)i * IN_DIM) + lane;
    float4 a = *o;
    a.x += v.x * nm; a.y += v.y * nm; a.z += v.z * nm; a.w += v.w * nm;
    *o = a;
}

// ---------------- fp32 tiled GEMM: C[M,N] = A[M,K] @ B[K,N] (+bias, relu) ----------------
template <bool RELU_BIAS>
__global__ __launch_bounds__(256) void gemm_kernel(const float* __restrict__ A,
                                                   const float* __restrict__ B,
                                                   const float* __restrict__ bias,
                                                   float* __restrict__ C,
                                                   int M, int N, int K) {
    constexpr int BM = 64, BN = 64, BK = 16, TM = 4, TN = 4;
    __shared__ float As[BK][BM + 4];
    __shared__ float Bs[BK][BN + 4];
    int tid = threadIdx.x;
    int tx = tid & 15;        // 16 col threads
    int ty = tid >> 4;        // 16 row threads
    int rowBase = blockIdx.y * BM;
    int colBase = blockIdx.x * BN;
    float acc[TM][TN] = {};
    for (int k0 = 0; k0 < K; k0 += BK) {
        // A tile: 64x16, 4 elems/thread
        #pragma unroll
        for (int t = 0; t < (BM * BK) / 256; t++) {
            int i = tid + t * 256;
            int r = i >> 4, c = i & 15;
            int gr = rowBase + r;
            As[c][r] = (gr < M) ? A[(size_t)gr * K + k0 + c] : 0.0f;
        }
        // B tile: 16x64, 4 elems/thread
        #pragma unroll
        for (int t = 0; t < (BK * BN) / 256; t++) {
            int i = tid + t * 256;
            int r = i >> 6, c = i & 63;
            Bs[r][c] = B[(size_t)(k0 + r) * N + colBase + c];
        }
        __syncthreads();
        #pragma unroll
        for (int k = 0; k < BK; k++) {
            float a[TM], b[TN];
            #pragma unroll
            for (int i = 0; i < TM; i++) a[i] = As[k][ty * TM + i];
            #pragma unroll
            for (int j = 0; j < TN; j++) b[j] = Bs[k][tx * TN + j];
            #pragma unroll
            for (int i = 0; i < TM; i++)
                #pragma unroll
                for (int j = 0; j < TN; j++)
                    acc[i][j] += a[i] * b[j];
        }
        __syncthreads();
    }
    #pragma unroll
    for (int i = 0; i < TM; i++) {
        int gr = rowBase + ty * TM + i;
        if (gr >= M) continue;
        #pragma unroll
        for (int j = 0; j < TN; j++) {
            int gc = colBase + tx * TN + j;
            float v = acc[i][j];
            if (RELU_BIAS) { v += bias[gc]; v = fmaxf(v, 0.0f); }
            C[(size_t)gr * N + gc] = v;
        }
    }
}

// ---------------- layer-2 scatter (transform-first, 64 dims, 16 lanes/edge) ----------------
__global__ void scatter2_kernel(const float* __restrict__ h2, const int* __restrict__ src,
                                const int* __restrict__ dst, const float* __restrict__ dis,
                                float* __restrict__ out, int E) {
    int sub = threadIdx.x & 15;
    int e = blockIdx.x * (blockDim.x >> 4) + (threadIdx.x >> 4);
    if (e >= E) return;
    int s = src[e], d = dst[e];
    float norm = dis[s] * dis[d];
    float4 v = ((const float4*)(h2 + (size_t)s * OUT_DIM))[sub];
    float* o = out + (size_t)d * OUT_DIM + sub * 4;
    atomicAdd(o + 0, v.x * norm);
    atomicAdd(o + 1, v.y * norm);
    atomicAdd(o + 2, v.z * norm);
    atomicAdd(o + 3, v.w * norm);
}

// ---------------- finalize: self-loop + b2 + log_softmax, one wave per row ----------------
__global__ void finalize_kernel(const float* __restrict__ h2, const float* __restrict__ dis,
                                const float* __restrict__ b2, float* __restrict__ out, int n) {
    int lane = threadIdx.x & 63;
    int row = blockIdx.x * (blockDim.x >> 6) + (threadIdx.x >> 6);
    if (row >= n) return;
    float nm = dis[row] * dis[row];
    size_t base = (size_t)row * OUT_DIM;
    float v = out[base + lane] + h2[base + lane] * nm + b2[lane];
    float m = v;
    #pragma unroll
    for (int off = 32; off > 0; off >>= 1) m = fmaxf(m, __shfl_xor(m, off, 64));
    float ex = expf(v - m);
    #pragma unroll
    for (int off = 32; off > 0; off >>= 1) ex += __shfl_xor(ex, off, 64);
    out[base + lane] = v - m - logf(ex);
}

extern "C" void kernel_launch(void* const* d_in, const int* in_sizes, int n_in,
                              void* d_out, int out_size, void* d_ws, size_t ws_size,
                              hipStream_t stream) {
    const float* x  = (const float*)d_in[0];
    const int*   ei = (const int*)d_in[1];
    const float* W1 = (const float*)d_in[2];
    const float* b1 = (const float*)d_in[3];
    const float* W2 = (const float*)d_in[4];
    const float* b2 = (const float*)d_in[5];
    float* out = (float*)d_out;
    char* ws = (char*)d_ws;

    const int* srcp = ei;
    const int* dstp = ei + N_EDGES;

    // workspace layout (16B aligned):
    float* dis  = (float*)(ws);                       // 50000 f32
    float* aggx = (float*)(ws + 262144);              // 50000*128 f32 = 25.6 MB
    float* h1   = (float*)(ws + 25862144);            // 50000*256 f32 = 51.2 MB
    float* h2   = (float*)(ws + 77062144);            // 50000*64  f32 = 12.8 MB

    hipMemsetAsync(dis, 0, (size_t)N_NODES * 4, stream);
    hipMemsetAsync(aggx, 0, (size_t)N_NODES * IN_DIM * 4, stream);
    hipMemsetAsync(out, 0, (size_t)N_NODES * OUT_DIM * 4, stream);

    deg_kernel<<<(N_EDGES + 255) / 256, 256, 0, stream>>>(dstp, dis, N_EDGES);
    dis_kernel<<<(N_NODES + 255) / 256, 256, 0, stream>>>(dis, N_NODES);

    // layer 1: aggregate-first (128 dims), then GEMM+bias+relu
    scatter1_kernel<<<(N_EDGES + 7) / 8, 256, 0, stream>>>(x, srcp, dstp, dis, aggx, N_EDGES);
    selfloop1_kernel<<<(N_NODES * 32 + 255) / 256, 256, 0, stream>>>(x, dis, aggx, N_NODES);
    gemm_kernel<true><<<dim3(HID_DIM / 64, (N_NODES + 63) / 64), 256, 0, stream>>>(
        aggx, W1, b1, h1, N_NODES, HID_DIM, IN_DIM);

    // layer 2: transform-first (64 dims), then scatter + finalize
    gemm_kernel<false><<<dim3(OUT_DIM / 64, (N_NODES + 63) / 64), 256, 0, stream>>>(
        h1, W2, nullptr, h2, N_NODES, OUT_DIM, HID_DIM);
    scatter2_kernel<<<(N_EDGES + 15) / 16, 256, 0, stream>>>(h2, srcp, dstp, dis, out, N_EDGES);
    finalize_kernel<<<(N_NODES + 3) / 4, 256, 0, stream>>>(h2, dis, b2, out, N_NODES);
}

// Round 2
// 395.488 us; speedup vs baseline: 5.7237x; 5.7237x over previous
//
#include <hip/hip_runtime.h>
#include <hip/hip_bf16.h>
#include <math.h>

#define N_NODES 50000
#define N_EDGES 800000
#define IN_DIM 128
#define HID_DIM 256
#define OUT_DIM 64

// ---------------- histogram of dst ----------------
__global__ void hist_kernel(const int* __restrict__ dst, int* __restrict__ cnt, int E) {
    int e = blockIdx.x * blockDim.x + threadIdx.x;
    if (e < E) atomicAdd(&cnt[dst[e]], 1);
}

__global__ void dis_kernel(const int* __restrict__ cnt, float* __restrict__ dis, int n) {
    int i = blockIdx.x * blockDim.x + threadIdx.x;
    if (i < n) dis[i] = rsqrtf((float)cnt[i] + 1.0f);   // +1 self-loop
}

// ---------------- exclusive scan (single block, wave shuffles) ----------------
__global__ __launch_bounds__(1024) void scan_kernel(const int* __restrict__ cnt,
                                                    int* __restrict__ offs,
                                                    int* __restrict__ cursor, int n) {
    __shared__ int wsum[16];
    __shared__ int run;
    int tid = threadIdx.x;
    int lane = tid & 63, wid = tid >> 6;
    if (tid == 0) run = 0;
    __syncthreads();
    for (int base = 0; base < n; base += 1024) {
        int i = base + tid;
        int v = (i < n) ? cnt[i] : 0;
        int s = v;
        #pragma unroll
        for (int off = 1; off < 64; off <<= 1) {
            int t = __shfl_up(s, off, 64);
            if (lane >= off) s += t;
        }
        if (lane == 63) wsum[wid] = s;
        __syncthreads();
        int wprefix = 0;
        #pragma unroll
        for (int w = 0; w < 16; w++) wprefix += (w < wid) ? wsum[w] : 0;
        int excl = s + wprefix - v;
        int r = run;
        if (i < n) { int o = r + excl; offs[i] = o; cursor[i] = o; }
        __syncthreads();
        if (tid == 0) {
            int tot = 0;
            #pragma unroll
            for (int w = 0; w < 16; w++) tot += wsum[w];
            run = r + tot;
        }
        __syncthreads();
    }
}

// ---------------- bucket edges by dst ----------------
__global__ void bucket_kernel(const int* __restrict__ src, const int* __restrict__ dst,
                              int* __restrict__ cursor, int* __restrict__ ssrc, int E) {
    int e = blockIdx.x * blockDim.x + threadIdx.x;
    if (e < E) {
        int d = dst[e];
        int pos = atomicAdd(&cursor[d], 1);
        ssrc[pos] = src[e];
    }
}

// ---------------- layer-1 aggregate: one wave per node, 2 edges/iter, 128 dims ----------------
__global__ void agg1_kernel(const float* __restrict__ x, const int* __restrict__ ssrc,
                            const int* __restrict__ offs, const int* __restrict__ cnt,
                            const float* __restrict__ dis, float* __restrict__ aggx, int n) {
    int lane = threadIdx.x & 63;
    int node = blockIdx.x * (blockDim.x >> 6) + (threadIdx.x >> 6);
    if (node >= n) return;
    int half = lane >> 5;   // 0 or 1
    int l32 = lane & 31;
    int start = offs[node], c = cnt[node];
    float dn = dis[node];
    float4 acc = {0.f, 0.f, 0.f, 0.f};
    for (int j = half; j < c; j += 2) {
        int s = ssrc[start + j];
        float nm = dis[s] * dn;
        float4 v = ((const float4*)(x + (size_t)s * IN_DIM))[l32];
        acc.x += v.x * nm; acc.y += v.y * nm; acc.z += v.z * nm; acc.w += v.w * nm;
    }
    acc.x += __shfl_xor(acc.x, 32, 64);
    acc.y += __shfl_xor(acc.y, 32, 64);
    acc.z += __shfl_xor(acc.z, 32, 64);
    acc.w += __shfl_xor(acc.w, 32, 64);
    if (half == 0) {
        float nm = dn * dn;
        float4 v = ((const float4*)(x + (size_t)node * IN_DIM))[l32];
        acc.x += v.x * nm; acc.y += v.y * nm; acc.z += v.z * nm; acc.w += v.w * nm;
        ((float4*)(aggx + (size_t)node * IN_DIM))[l32] = acc;
    }
}

// ---------------- fp32 tiled GEMM: C[M,N] = A[M,K] @ B[K,N] (+bias, relu) ----------------
template <bool RELU_BIAS>
__global__ __launch_bounds__(256) void gemm_kernel(const float* __restrict__ A,
                                                   const float* __restrict__ B,
                                                   const float* __restrict__ bias,
                                                   float* __restrict__ C,
                                                   int M, int N, int K) {
    constexpr int BM = 64, BN = 64, BK = 16, TM = 4, TN = 4;
    __shared__ float As[BK][BM + 4];
    __shared__ float Bs[BK][BN + 4];
    int tid = threadIdx.x;
    int tx = tid & 15;
    int ty = tid >> 4;
    int rowBase = blockIdx.y * BM;
    int colBase = blockIdx.x * BN;
    float acc[TM][TN] = {};
    for (int k0 = 0; k0 < K; k0 += BK) {
        #pragma unroll
        for (int t = 0; t < (BM * BK) / 256; t++) {
            int i = tid + t * 256;
            int r = i >> 4, c = i & 15;
            int gr = rowBase + r;
            As[c][r] = (gr < M) ? A[(size_t)gr * K + k0 + c] : 0.0f;
        }
        #pragma unroll
        for (int t = 0; t < (BK * BN) / 256; t++) {
            int i = tid + t * 256;
            int r = i >> 6, c = i & 63;
            Bs[r][c] = B[(size_t)(k0 + r) * N + colBase + c];
        }
        __syncthreads();
        #pragma unroll
        for (int k = 0; k < BK; k++) {
            float a[TM], b[TN];
            #pragma unroll
            for (int i = 0; i < TM; i++) a[i] = As[k][ty * TM + i];
            #pragma unroll
            for (int j = 0; j < TN; j++) b[j] = Bs[k][tx * TN + j];
            #pragma unroll
            for (int i = 0; i < TM; i++)
                #pragma unroll
                for (int j = 0; j < TN; j++)
                    acc[i][j] += a[i] * b[j];
        }
        __syncthreads();
    }
    #pragma unroll
    for (int i = 0; i < TM; i++) {
        int gr = rowBase + ty * TM + i;
        if (gr >= M) continue;
        #pragma unroll
        for (int j = 0; j < TN; j++) {
            int gc = colBase + tx * TN + j;
            float v = acc[i][j];
            if (RELU_BIAS) { v += bias[gc]; v = fmaxf(v, 0.0f); }
            C[(size_t)gr * N + gc] = v;
        }
    }
}

// ---------------- layer-2 aggregate + self-loop + bias + log_softmax fused ----------------
__global__ void agg2_kernel(const float* __restrict__ h2, const int* __restrict__ ssrc,
                            const int* __restrict__ offs, const int* __restrict__ cnt,
                            const float* __restrict__ dis, const float* __restrict__ b2,
                            float* __restrict__ out, int n) {
    int lane = threadIdx.x & 63;
    int node = blockIdx.x * (blockDim.x >> 6) + (threadIdx.x >> 6);
    if (node >= n) return;
    int grp = lane >> 4;     // 0..3
    int l16 = lane & 15;
    int start = offs[node], c = cnt[node];
    float dn = dis[node];
    float4 acc = {0.f, 0.f, 0.f, 0.f};
    for (int j = grp; j < c; j += 4) {
        int s = ssrc[start + j];
        float nm = dis[s] * dn;
        float4 v = ((const float4*)(h2 + (size_t)s * OUT_DIM))[l16];
        acc.x += v.x * nm; acc.y += v.y * nm; acc.z += v.z * nm; acc.w += v.w * nm;
    }
    // reduce the 4 groups (xor 16, 32 leaves full sum in all lanes)
    acc.x += __shfl_xor(acc.x, 16, 64); acc.y += __shfl_xor(acc.y, 16, 64);
    acc.z += __shfl_xor(acc.z, 16, 64); acc.w += __shfl_xor(acc.w, 16, 64);
    acc.x += __shfl_xor(acc.x, 32, 64); acc.y += __shfl_xor(acc.y, 32, 64);
    acc.z += __shfl_xor(acc.z, 32, 64); acc.w += __shfl_xor(acc.w, 32, 64);
    // self-loop + bias
    float nm = dn * dn;
    float4 v = ((const float4*)(h2 + (size_t)node * OUT_DIM))[l16];
    float4 bb = ((const float4*)b2)[l16];
    acc.x += v.x * nm + bb.x; acc.y += v.y * nm + bb.y;
    acc.z += v.z * nm + bb.z; acc.w += v.w * nm + bb.w;
    // log_softmax over 64 cols (16 l16-groups x 4 regs)
    float m = fmaxf(fmaxf(acc.x, acc.y), fmaxf(acc.z, acc.w));
    #pragma unroll
    for (int off = 1; off < 16; off <<= 1) m = fmaxf(m, __shfl_xor(m, off, 64));
    float ex = expf(acc.x - m) + expf(acc.y - m) + expf(acc.z - m) + expf(acc.w - m);
    #pragma unroll
    for (int off = 1; off < 16; off <<= 1) ex += __shfl_xor(ex, off, 64);
    float ls = m + logf(ex);
    if (grp == 0) {
        float4 o = {acc.x - ls, acc.y - ls, acc.z - ls, acc.w - ls};
        ((float4*)(out + (size_t)node * OUT_DIM))[l16] = o;
    }
}

extern "C" void kernel_launch(void* const* d_in, const int* in_sizes, int n_in,
                              void* d_out, int out_size, void* d_ws, size_t ws_size,
                              hipStream_t stream) {
    const float* x  = (const float*)d_in[0];
    const int*   ei = (const int*)d_in[1];
    const float* W1 = (const float*)d_in[2];
    const float* b1 = (const float*)d_in[3];
    const float* W2 = (const float*)d_in[4];
    const float* b2 = (const float*)d_in[5];
    float* out = (float*)d_out;
    char* ws = (char*)d_ws;

    const int* srcp = ei;
    const int* dstp = ei + N_EDGES;

    // workspace layout
    int*   cnt    = (int*)(ws);                    // 50000 int
    int*   offs   = (int*)(ws + 262144);           // 50000 int
    int*   cursor = (int*)(ws + 524288);           // 50000 int
    float* dis    = (float*)(ws + 786432);         // 50000 f32
    int*   ssrc   = (int*)(ws + 1048576);          // 800000 int = 3.2 MB
    float* aggx   = (float*)(ws + 4456448);        // 50000*128 f32 = 25.6 MB
    float* h1     = (float*)(ws + 30408704);       // 50000*256 f32 = 51.2 MB
    float* h2     = aggx;                          // reuse (12.8 MB <= 25.6 MB, aggx dead after gemm1)

    hipMemsetAsync(cnt, 0, (size_t)N_NODES * 4, stream);

    hist_kernel<<<(N_EDGES + 255) / 256, 256, 0, stream>>>(dstp, cnt, N_EDGES);
    dis_kernel<<<(N_NODES + 255) / 256, 256, 0, stream>>>(cnt, dis, N_NODES);
    scan_kernel<<<1, 1024, 0, stream>>>(cnt, offs, cursor, N_NODES);
    bucket_kernel<<<(N_EDGES + 255) / 256, 256, 0, stream>>>(srcp, dstp, cursor, ssrc, N_EDGES);

    // layer 1: aggregate-first (128 dims), then GEMM+bias+relu
    agg1_kernel<<<(N_NODES + 3) / 4, 256, 0, stream>>>(x, ssrc, offs, cnt, dis, aggx, N_NODES);
    gemm_kernel<true><<<dim3(HID_DIM / 64, (N_NODES + 63) / 64), 256, 0, stream>>>(
        aggx, W1, b1, h1, N_NODES, HID_DIM, IN_DIM);

    // layer 2: transform-first (64 dims), then fused aggregate+softmax
    gemm_kernel<false><<<dim3(OUT_DIM / 64, (N_NODES + 63) / 64), 256, 0, stream>>>(
        h1, W2, nullptr, h2, N_NODES, OUT_DIM, HID_DIM);
    agg2_kernel<<<(N_NODES + 3) / 4, 256, 0, stream>>>(h2, ssrc, offs, cnt, dis, b2, out, N_NODES);
}

// Round 3
// 301.927 us; speedup vs baseline: 7.4974x; 1.3099x over previous
//
#include <hip/hip_runtime.h>
#include <hip/hip_bf16.h>
#include <math.h>

#define N_NODES 50000
#define N_EDGES 800000
#define IN_DIM 128
#define HID_DIM 256
#define OUT_DIM 64

typedef __attribute__((ext_vector_type(8))) short bf16x8;
typedef __attribute__((ext_vector_type(4))) short short4v;
typedef __attribute__((ext_vector_type(4))) float f32x4;

__device__ inline short f2bf(float f) {   // round-to-nearest-even bf16
    unsigned u = __float_as_uint(f);
    unsigned r = (u + 0x7fffu + ((u >> 16) & 1u)) >> 16;
    return (short)r;
}

// ---------------- histogram of dst ----------------
__global__ void hist_kernel(const int* __restrict__ dst, int* __restrict__ cnt, int E) {
    int e = blockIdx.x * blockDim.x + threadIdx.x;
    if (e < E) atomicAdd(&cnt[dst[e]], 1);
}

__global__ void dis_kernel(const int* __restrict__ cnt, float* __restrict__ dis, int n) {
    int i = blockIdx.x * blockDim.x + threadIdx.x;
    if (i < n) dis[i] = rsqrtf((float)cnt[i] + 1.0f);   // +1 self-loop
}

// ---------------- hierarchical exclusive scan ----------------
__global__ __launch_bounds__(256) void scan1_kernel(const int* __restrict__ cnt,
                                                    int* __restrict__ offs,
                                                    int* __restrict__ bsum, int n) {
    __shared__ int ws[4];
    int tid = threadIdx.x, lane = tid & 63, wid = tid >> 6;
    int i = blockIdx.x * 256 + tid;
    int v = (i < n) ? cnt[i] : 0;
    int s = v;
    #pragma unroll
    for (int off = 1; off < 64; off <<= 1) {
        int t = __shfl_up(s, off, 64);
        if (lane >= off) s += t;
    }
    if (lane == 63) ws[wid] = s;
    __syncthreads();
    int wp = 0;
    #pragma unroll
    for (int w = 0; w < 4; w++) wp += (w < wid) ? ws[w] : 0;
    int excl = s - v + wp;
    if (i < n) offs[i] = excl;
    if (tid == 255) bsum[blockIdx.x] = excl + v;
}

__global__ __launch_bounds__(256) void scan2_kernel(int* __restrict__ bsum, int nb) {
    __shared__ int ws[4];
    int tid = threadIdx.x, lane = tid & 63, wid = tid >> 6;
    int v = (tid < nb) ? bsum[tid] : 0;
    int s = v;
    #pragma unroll
    for (int off = 1; off < 64; off <<= 1) {
        int t = __shfl_up(s, off, 64);
        if (lane >= off) s += t;
    }
    if (lane == 63) ws[wid] = s;
    __syncthreads();
    int wp = 0;
    #pragma unroll
    for (int w = 0; w < 4; w++) wp += (w < wid) ? ws[w] : 0;
    if (tid < nb) bsum[tid] = s - v + wp;
}

__global__ void scan3_kernel(int* __restrict__ offs, const int* __restrict__ bsum,
                             int* __restrict__ cursor, int n) {
    int i = blockIdx.x * 256 + threadIdx.x;
    if (i < n) {
        int o = offs[i] + bsum[blockIdx.x];
        offs[i] = o;
        cursor[i] = o;
    }
}

// ---------------- bucket edges by dst ----------------
__global__ void bucket_kernel(const int* __restrict__ src, const int* __restrict__ dst,
                              int* __restrict__ cursor, int* __restrict__ ssrc, int E) {
    int e = blockIdx.x * blockDim.x + threadIdx.x;
    if (e < E) {
        int d = dst[e];
        int pos = atomicAdd(&cursor[d], 1);
        ssrc[pos] = src[e];
    }
}

// ---------------- pack W[K,N] fp32 -> MFMA B-frag order bf16 ----------------
// Bp[((kt*(N/16)+nt)*64 + lane)*8 + j] = bf16(W[kt*32 + (lane>>4)*8 + j][nt*16 + (lane&15)])
__global__ void pack_kernel(const float* __restrict__ W, short* __restrict__ Bp, int K, int N) {
    int idx = blockIdx.x * blockDim.x + threadIdx.x;
    int total = (K >> 5) * (N >> 4) * 64;
    if (idx >= total) return;
    int lane = idx & 63;
    int frag = idx >> 6;
    int ntiles = N >> 4;
    int nt = frag % ntiles;
    int kt = frag / ntiles;
    int col = nt * 16 + (lane & 15);
    int krow = kt * 32 + (lane >> 4) * 8;
    short v[8];
    #pragma unroll
    for (int j = 0; j < 8; j++) v[j] = f2bf(W[(size_t)(krow + j) * N + col]);
    bf16x8 pk;
    #pragma unroll
    for (int j = 0; j < 8; j++) pk[j] = v[j];
    *((bf16x8*)(Bp + (size_t)idx * 8)) = pk;
}

// ---------------- layer-1 aggregate: one wave per node, fp32 gather, bf16 write --------
__global__ void agg1_kernel(const float* __restrict__ x, const int* __restrict__ ssrc,
                            const int* __restrict__ offs, const int* __restrict__ cnt,
                            const float* __restrict__ dis, short* __restrict__ aggx, int n) {
    int lane = threadIdx.x & 63;
    int node = blockIdx.x * (blockDim.x >> 6) + (threadIdx.x >> 6);
    if (node >= n) return;
    int half = lane >> 5;
    int l32 = lane & 31;
    int start = offs[node], c = cnt[node];
    float dn = dis[node];
    float4 acc = {0.f, 0.f, 0.f, 0.f};
    for (int j = half; j < c; j += 2) {
        int s = ssrc[start + j];
        float nm = dis[s] * dn;
        float4 v = ((const float4*)(x + (size_t)s * IN_DIM))[l32];
        acc.x += v.x * nm; acc.y += v.y * nm; acc.z += v.z * nm; acc.w += v.w * nm;
    }
    acc.x += __shfl_xor(acc.x, 32, 64);
    acc.y += __shfl_xor(acc.y, 32, 64);
    acc.z += __shfl_xor(acc.z, 32, 64);
    acc.w += __shfl_xor(acc.w, 32, 64);
    if (half == 0) {
        float nm = dn * dn;
        float4 v = ((const float4*)(x + (size_t)node * IN_DIM))[l32];
        acc.x += v.x * nm; acc.y += v.y * nm; acc.z += v.z * nm; acc.w += v.w * nm;
        short4v o = {f2bf(acc.x), f2bf(acc.y), f2bf(acc.z), f2bf(acc.w)};
        *((short4v*)(aggx + (size_t)node * IN_DIM + l32 * 4)) = o;
    }
}

// ---------------- LDS-free MFMA GEMM: C[M,N] = A[M,K](bf16) @ Bp(packed bf16) ----------
// 4 waves/block, each wave owns 16 rows x N cols. A-frag: 16B direct global load.
template <int K, int NT, bool OUT_BF16, bool RELU>
__global__ __launch_bounds__(256) void gemm_mfma(const short* __restrict__ A,
                                                 const short* __restrict__ Bp,
                                                 const float* __restrict__ bias,
                                                 void* __restrict__ C, int M, int N) {
    int lane = threadIdx.x & 63;
    int w = threadIdx.x >> 6;
    int rowBase = blockIdx.x * 64 + w * 16;
    int arow = rowBase + (lane & 15);
    int kseg = lane >> 4;             // 0..3
    f32x4 acc[NT] = {};
    constexpr int KT = K / 32;
    #pragma unroll
    for (int kt = 0; kt < KT; kt++) {
        bf16x8 a = {};
        if (arow < M)
            a = *((const bf16x8*)(A + (size_t)arow * K + kt * 32 + kseg * 8));
        #pragma unroll
        for (int nt = 0; nt < NT; nt++) {
            bf16x8 b = *((const bf16x8*)(Bp + ((size_t)(kt * NT + nt) * 64 + lane) * 8));
            acc[nt] = __builtin_amdgcn_mfma_f32_16x16x32_bf16(a, b, acc[nt], 0, 0, 0);
        }
    }
    // epilogue: C/D layout col=lane&15, row=(lane>>4)*4+i
    int col0 = lane & 15;
    #pragma unroll
    for (int nt = 0; nt < NT; nt++) {
        int col = nt * 16 + col0;
        float bv = RELU ? bias[col] : 0.0f;
        #pragma unroll
        for (int i = 0; i < 4; i++) {
            int r = rowBase + kseg * 4 + i;
            if (r >= M) continue;
            float v = acc[nt][i];
            if (RELU) { v += bv; v = fmaxf(v, 0.0f); }
            if (OUT_BF16) ((short*)C)[(size_t)r * N + col] = f2bf(v);
            else ((float*)C)[(size_t)r * N + col] = v;
        }
    }
}

// ---------------- layer-2 aggregate + self-loop + bias + log_softmax fused ----------------
__global__ void agg2_kernel(const float* __restrict__ h2, const int* __restrict__ ssrc,
                            const int* __restrict__ offs, const int* __restrict__ cnt,
                            const float* __restrict__ dis, const float* __restrict__ b2,
                            float* __restrict__ out, int n) {
    int lane = threadIdx.x & 63;
    int node = blockIdx.x * (blockDim.x >> 6) + (threadIdx.x >> 6);
    if (node >= n) return;
    int grp = lane >> 4;
    int l16 = lane & 15;
    int start = offs[node], c = cnt[node];
    float dn = dis[node];
    float4 acc = {0.f, 0.f, 0.f, 0.f};
    for (int j = grp; j < c; j += 4) {
        int s = ssrc[start + j];
        float nm = dis[s] * dn;
        float4 v = ((const float4*)(h2 + (size_t)s * OUT_DIM))[l16];
        acc.x += v.x * nm; acc.y += v.y * nm; acc.z += v.z * nm; acc.w += v.w * nm;
    }
    acc.x += __shfl_xor(acc.x, 16, 64); acc.y += __shfl_xor(acc.y, 16, 64);
    acc.z += __shfl_xor(acc.z, 16, 64); acc.w += __shfl_xor(acc.w, 16, 64);
    acc.x += __shfl_xor(acc.x, 32, 64); acc.y += __shfl_xor(acc.y, 32, 64);
    acc.z += __shfl_xor(acc.z, 32, 64); acc.w += __shfl_xor(acc.w, 32, 64);
    float nm = dn * dn;
    float4 v = ((const float4*)(h2 + (size_t)node * OUT_DIM))[l16];
    float4 bb = ((const float4*)b2)[l16];
    acc.x += v.x * nm + bb.x; acc.y += v.y * nm + bb.y;
    acc.z += v.z * nm + bb.z; acc.w += v.w * nm + bb.w;
    float m = fmaxf(fmaxf(acc.x, acc.y), fmaxf(acc.z, acc.w));
    #pragma unroll
    for (int off = 1; off < 16; off <<= 1) m = fmaxf(m, __shfl_xor(m, off, 64));
    float ex = expf(acc.x - m) + expf(acc.y - m) + expf(acc.z - m) + expf(acc.w - m);
    #pragma unroll
    for (int off = 1; off < 16; off <<= 1) ex += __shfl_xor(ex, off, 64);
    float ls = m + logf(ex);
    if (grp == 0) {
        float4 o = {acc.x - ls, acc.y - ls, acc.z - ls, acc.w - ls};
        ((float4*)(out + (size_t)node * OUT_DIM))[l16] = o;
    }
}

extern "C" void kernel_launch(void* const* d_in, const int* in_sizes, int n_in,
                              void* d_out, int out_size, void* d_ws, size_t ws_size,
                              hipStream_t stream) {
    const float* x  = (const float*)d_in[0];
    const int*   ei = (const int*)d_in[1];
    const float* W1 = (const float*)d_in[2];
    const float* b1 = (const float*)d_in[3];
    const float* W2 = (const float*)d_in[4];
    const float* b2 = (const float*)d_in[5];
    float* out = (float*)d_out;
    char* ws = (char*)d_ws;

    const int* srcp = ei;
    const int* dstp = ei + N_EDGES;

    // workspace layout (all 256-aligned)
    int*   cnt    = (int*)(ws);                    // 50000 int
    int*   offs   = (int*)(ws + 262144);
    int*   cursor = (int*)(ws + 524288);
    float* dis    = (float*)(ws + 786432);
    int*   bsum   = (int*)(ws + 1048576);          // 196 int
    short* Bp1    = (short*)(ws + 1052672);        // 128*256 bf16 = 64 KB
    short* Bp2    = (short*)(ws + 1118208);        // 256*64 bf16 = 32 KB
    int*   ssrc   = (int*)(ws + 1310720);          // 800000 int = 3.2 MB
    short* aggx   = (short*)(ws + 4718592);        // 50000*128 bf16 = 12.8 MB
    short* h1     = (short*)(ws + 17563648);       // 50000*256 bf16 = 25.6 MB
    float* h2     = (float*)(ws + 43253760);       // 50000*64 f32 = 12.8 MB

    hipMemsetAsync(cnt, 0, (size_t)N_NODES * 4, stream);

    hist_kernel<<<(N_EDGES + 255) / 256, 256, 0, stream>>>(dstp, cnt, N_EDGES);
    dis_kernel<<<(N_NODES + 255) / 256, 256, 0, stream>>>(cnt, dis, N_NODES);

    const int NB = (N_NODES + 255) / 256;          // 196
    scan1_kernel<<<NB, 256, 0, stream>>>(cnt, offs, bsum, N_NODES);
    scan2_kernel<<<1, 256, 0, stream>>>(bsum, NB);
    scan3_kernel<<<NB, 256, 0, stream>>>(offs, bsum, cursor, N_NODES);
    bucket_kernel<<<(N_EDGES + 255) / 256, 256, 0, stream>>>(srcp, dstp, cursor, ssrc, N_EDGES);

    // pack weights into MFMA B-frag order (bf16)
    pack_kernel<<<(4096 + 255) / 256, 256, 0, stream>>>(W1, Bp1, IN_DIM, HID_DIM);
    pack_kernel<<<(2048 + 255) / 256, 256, 0, stream>>>(W2, Bp2, HID_DIM, OUT_DIM);

    // layer 1: aggregate-first (fp32 gather -> bf16 aggx), then MFMA GEMM (+bias+relu) -> bf16 h1
    agg1_kernel<<<(N_NODES + 3) / 4, 256, 0, stream>>>(x, ssrc, offs, cnt, dis, aggx, N_NODES);
    gemm_mfma<IN_DIM, HID_DIM / 16, true, true>
        <<<(N_NODES + 63) / 64, 256, 0, stream>>>(aggx, Bp1, b1, h1, N_NODES, HID_DIM);

    // layer 2: transform-first MFMA GEMM -> fp32 h2, then fused aggregate+softmax
    gemm_mfma<HID_DIM, OUT_DIM / 16, false, false>
        <<<(N_NODES + 63) / 64, 256, 0, stream>>>(h1, Bp2, nullptr, h2, N_NODES, OUT_DIM);
    agg2_kernel<<<(N_NODES + 3) / 4, 256, 0, stream>>>(h2, ssrc, offs, cnt, dis, b2, out, N_NODES);
}

// Round 4
// 285.064 us; speedup vs baseline: 7.9409x; 1.0592x over previous
//
#include <hip/hip_runtime.h>
#include <hip/hip_bf16.h>
#include <math.h>

#define N_NODES 50000
#define N_EDGES 800000
#define IN_DIM 128
#define HID_DIM 256
#define OUT_DIM 64

typedef __attribute__((ext_vector_type(8))) short bf16x8;
typedef __attribute__((ext_vector_type(4))) short short4v;
typedef __attribute__((ext_vector_type(4))) float f32x4;

__device__ inline short f2bf(float f) {   // round-to-nearest-even bf16
    unsigned u = __float_as_uint(f);
    unsigned r = (u + 0x7fffu + ((u >> 16) & 1u)) >> 16;
    return (short)r;
}
__device__ inline float bf_lo(unsigned u) { return __uint_as_float(u << 16); }
__device__ inline float bf_hi(unsigned u) { return __uint_as_float(u & 0xffff0000u); }

// ---------------- prep: x -> bf16, zero cnt + global counter ----------------
__global__ void prep_kernel(const float* __restrict__ x, short* __restrict__ xb,
                            int* __restrict__ cnt, int* __restrict__ gcnt) {
    int idx = blockIdx.x * blockDim.x + threadIdx.x;   // exactly N_NODES*IN_DIM/4 threads
    float4 v = ((const float4*)x)[idx];
    short4v o = {f2bf(v.x), f2bf(v.y), f2bf(v.z), f2bf(v.w)};
    ((short4v*)xb)[idx] = o;
    if (idx < N_NODES) cnt[idx] = 0;
    if (idx == 0) *gcnt = 0;
}

// ---------------- histogram of dst ----------------
__global__ void hist_kernel(const int* __restrict__ dst, int* __restrict__ cnt, int E) {
    int e = blockIdx.x * blockDim.x + threadIdx.x;
    if (e < E) atomicAdd(&cnt[dst[e]], 1);
}

// ---------------- single-dispatch scan: block-local prefix + atomic base; + dis ------
// Bucket ORDER across blocks is non-deterministic, which is fine: each node only
// needs some contiguous range of size cnt[node].
__global__ __launch_bounds__(256) void scan_kernel(const int* __restrict__ cnt,
                                                   int* __restrict__ offs,
                                                   int* __restrict__ cursor,
                                                   float* __restrict__ dis,
                                                   int* __restrict__ gcnt, int n) {
    __shared__ int ws[4];
    __shared__ int base;
    int tid = threadIdx.x, lane = tid & 63, wid = tid >> 6;
    int i = blockIdx.x * 256 + tid;
    int v = (i < n) ? cnt[i] : 0;
    int s = v;
    #pragma unroll
    for (int off = 1; off < 64; off <<= 1) {
        int t = __shfl_up(s, off, 64);
        if (lane >= off) s += t;
    }
    if (lane == 63) ws[wid] = s;
    __syncthreads();
    int wp = 0;
    #pragma unroll
    for (int w = 0; w < 4; w++) wp += (w < wid) ? ws[w] : 0;
    int excl = s - v + wp;
    if (tid == 255) base = atomicAdd(gcnt, excl + v);
    __syncthreads();
    if (i < n) {
        int o = base + excl;
        offs[i] = o;
        cursor[i] = o;
        dis[i] = rsqrtf((float)v + 1.0f);   // +1 self-loop
    }
}

// ---------------- bucket edges by dst ----------------
__global__ void bucket_kernel(const int* __restrict__ src, const int* __restrict__ dst,
                              int* __restrict__ cursor, int* __restrict__ ssrc, int E) {
    int e = blockIdx.x * blockDim.x + threadIdx.x;
    if (e < E) {
        int d = dst[e];
        int pos = atomicAdd(&cursor[d], 1);
        ssrc[pos] = src[e];
    }
}

// ---------------- pack BOTH weight matrices -> MFMA B-frag order bf16 ----------------
// Bp[frag*512 + lane*8 + j] = bf16(W[kt*32 + (lane>>4)*8 + j][nt*16 + (lane&15)])
__global__ void pack_kernel(const float* __restrict__ W1, const float* __restrict__ W2,
                            short* __restrict__ Bp1, short* __restrict__ Bp2) {
    int idx = blockIdx.x * blockDim.x + threadIdx.x;
    const float* W; short* Bp; int N;
    const int T1 = (IN_DIM / 32) * (HID_DIM / 16) * 64;    // 4096
    const int T2 = (HID_DIM / 32) * (OUT_DIM / 16) * 64;   // 2048
    if (idx < T1) { W = W1; Bp = Bp1; N = HID_DIM; }
    else { idx -= T1; if (idx >= T2) return; W = W2; Bp = Bp2; N = OUT_DIM; }
    int lane = idx & 63;
    int frag = idx >> 6;
    int ntiles = N >> 4;
    int nt = frag % ntiles;
    int kt = frag / ntiles;
    int col = nt * 16 + (lane & 15);
    int krow = kt * 32 + (lane >> 4) * 8;
    bf16x8 pk;
    #pragma unroll
    for (int j = 0; j < 8; j++) pk[j] = f2bf(W[(size_t)(krow + j) * N + col]);
    *((bf16x8*)(Bp + (size_t)idx * 8)) = pk;
}

// ---------------- layer-1 aggregate: one wave per node, bf16 gather (256B rows) ------
__global__ void agg1_kernel(const short* __restrict__ xb, const int* __restrict__ ssrc,
                            const int* __restrict__ offs, const int* __restrict__ cnt,
                            const float* __restrict__ dis, short* __restrict__ aggx, int n) {
    int lane = threadIdx.x & 63;
    int node = blockIdx.x * (blockDim.x >> 6) + (threadIdx.x >> 6);
    if (node >= n) return;
    int grp = lane >> 4, l16 = lane & 15;
    int start = offs[node], c = cnt[node];
    float dn = dis[node];
    float acc[8] = {};
    for (int j = grp; j < c; j += 4) {
        int s = ssrc[start + j];
        float nm = dis[s] * dn;
        uint4 pk = *((const uint4*)(xb + (size_t)s * IN_DIM + l16 * 8));
        acc[0] += bf_lo(pk.x) * nm; acc[1] += bf_hi(pk.x) * nm;
        acc[2] += bf_lo(pk.y) * nm; acc[3] += bf_hi(pk.y) * nm;
        acc[4] += bf_lo(pk.z) * nm; acc[5] += bf_hi(pk.z) * nm;
        acc[6] += bf_lo(pk.w) * nm; acc[7] += bf_hi(pk.w) * nm;
    }
    #pragma unroll
    for (int k = 0; k < 8; k++) {
        acc[k] += __shfl_xor(acc[k], 16, 64);
        acc[k] += __shfl_xor(acc[k], 32, 64);
    }
    if (grp == 0) {
        float nm = dn * dn;
        uint4 pk = *((const uint4*)(xb + (size_t)node * IN_DIM + l16 * 8));
        acc[0] += bf_lo(pk.x) * nm; acc[1] += bf_hi(pk.x) * nm;
        acc[2] += bf_lo(pk.y) * nm; acc[3] += bf_hi(pk.y) * nm;
        acc[4] += bf_lo(pk.z) * nm; acc[5] += bf_hi(pk.z) * nm;
        acc[6] += bf_lo(pk.w) * nm; acc[7] += bf_hi(pk.w) * nm;
        bf16x8 o;
        #pragma unroll
        for (int k = 0; k < 8; k++) o[k] = f2bf(acc[k]);
        *((bf16x8*)(aggx + (size_t)node * IN_DIM + l16 * 8)) = o;
    }
}

// ---------------- LDS-free MFMA GEMM: C[M,N] = A[M,K](bf16) @ Bp(packed bf16) ----------
template <int K, int NT, bool OUT_BF16, bool RELU>
__global__ __launch_bounds__(256) void gemm_mfma(const short* __restrict__ A,
                                                 const short* __restrict__ Bp,
                                                 const float* __restrict__ bias,
                                                 void* __restrict__ C, int M, int N) {
    int lane = threadIdx.x & 63;
    int w = threadIdx.x >> 6;
    int rowBase = blockIdx.x * 64 + w * 16;
    int arow = rowBase + (lane & 15);
    int kseg = lane >> 4;             // 0..3
    f32x4 acc[NT] = {};
    constexpr int KT = K / 32;
    #pragma unroll
    for (int kt = 0; kt < KT; kt++) {
        bf16x8 a = {};
        if (arow < M)
            a = *((const bf16x8*)(A + (size_t)arow * K + kt * 32 + kseg * 8));
        #pragma unroll
        for (int nt = 0; nt < NT; nt++) {
            bf16x8 b = *((const bf16x8*)(Bp + ((size_t)(kt * NT + nt) * 64 + lane) * 8));
            acc[nt] = __builtin_amdgcn_mfma_f32_16x16x32_bf16(a, b, acc[nt], 0, 0, 0);
        }
    }
    // epilogue: C/D layout col=lane&15, row=(lane>>4)*4+i
    int col0 = lane & 15;
    #pragma unroll
    for (int nt = 0; nt < NT; nt++) {
        int col = nt * 16 + col0;
        float bv = RELU ? bias[col] : 0.0f;
        #pragma unroll
        for (int i = 0; i < 4; i++) {
            int r = rowBase + kseg * 4 + i;
            if (r >= M) continue;
            float v = acc[nt][i];
            if (RELU) { v += bv; v = fmaxf(v, 0.0f); }
            if (OUT_BF16) ((short*)C)[(size_t)r * N + col] = f2bf(v);
            else ((float*)C)[(size_t)r * N + col] = v;
        }
    }
}

// ---------------- layer-2 aggregate (bf16 gather) + self-loop + bias + log_softmax ----
__global__ void agg2_kernel(const short* __restrict__ h2, const int* __restrict__ ssrc,
                            const int* __restrict__ offs, const int* __restrict__ cnt,
                            const float* __restrict__ dis, const float* __restrict__ b2,
                            float* __restrict__ out, int n) {
    int lane = threadIdx.x & 63;
    int node = blockIdx.x * (blockDim.x >> 6) + (threadIdx.x >> 6);
    if (node >= n) return;
    int grp = lane >> 4, l16 = lane & 15;
    int start = offs[node], c = cnt[node];
    float dn = dis[node];
    float acc[4] = {};
    for (int j = grp; j < c; j += 4) {
        int s = ssrc[start + j];
        float nm = dis[s] * dn;
        uint2 pk = *((const uint2*)(h2 + (size_t)s * OUT_DIM + l16 * 4));
        acc[0] += bf_lo(pk.x) * nm; acc[1] += bf_hi(pk.x) * nm;
        acc[2] += bf_lo(pk.y) * nm; acc[3] += bf_hi(pk.y) * nm;
    }
    #pragma unroll
    for (int k = 0; k < 4; k++) {
        acc[k] += __shfl_xor(acc[k], 16, 64);
        acc[k] += __shfl_xor(acc[k], 32, 64);
    }
    // self-loop + bias (all lanes; values identical across the 4 grps)
    float nm = dn * dn;
    uint2 pk = *((const uint2*)(h2 + (size_t)node * OUT_DIM + l16 * 4));
    float4 bb = ((const float4*)b2)[l16];
    acc[0] += bf_lo(pk.x) * nm + bb.x; acc[1] += bf_hi(pk.x) * nm + bb.y;
    acc[2] += bf_lo(pk.y) * nm + bb.z; acc[3] += bf_hi(pk.y) * nm + bb.w;
    // log_softmax over 64 cols (16 l16-groups x 4 regs)
    float m = fmaxf(fmaxf(acc[0], acc[1]), fmaxf(acc[2], acc[3]));
    #pragma unroll
    for (int off = 1; off < 16; off <<= 1) m = fmaxf(m, __shfl_xor(m, off, 64));
    float ex = expf(acc[0] - m) + expf(acc[1] - m) + expf(acc[2] - m) + expf(acc[3] - m);
    #pragma unroll
    for (int off = 1; off < 16; off <<= 1) ex += __shfl_xor(ex, off, 64);
    float ls = m + logf(ex);
    if (grp == 0) {
        float4 o = {acc[0] - ls, acc[1] - ls, acc[2] - ls, acc[3] - ls};
        ((float4*)(out + (size_t)node * OUT_DIM))[l16] = o;
    }
}

extern "C" void kernel_launch(void* const* d_in, const int* in_sizes, int n_in,
                              void* d_out, int out_size, void* d_ws, size_t ws_size,
                              hipStream_t stream) {
    const float* x  = (const float*)d_in[0];
    const int*   ei = (const int*)d_in[1];
    const float* W1 = (const float*)d_in[2];
    const float* b1 = (const float*)d_in[3];
    const float* W2 = (const float*)d_in[4];
    const float* b2 = (const float*)d_in[5];
    float* out = (float*)d_out;
    char* ws = (char*)d_ws;

    const int* srcp = ei;
    const int* dstp = ei + N_EDGES;

    // workspace layout (256-aligned)
    int*   cnt    = (int*)(ws);                    // 50000 int
    int*   offs   = (int*)(ws + 262144);
    int*   cursor = (int*)(ws + 524288);
    float* dis    = (float*)(ws + 786432);
    int*   gcnt   = (int*)(ws + 1048576);          // 1 int
    short* Bp1    = (short*)(ws + 1052672);        // 64 KB
    short* Bp2    = (short*)(ws + 1118208);        // 32 KB
    int*   ssrc   = (int*)(ws + 1310720);          // 3.2 MB
    short* xb     = (short*)(ws + 4718592);        // 12.8 MB
    short* aggx   = (short*)(ws + 17563648);       // 12.8 MB
    short* h1     = (short*)(ws + 30408704);       // 25.6 MB
    short* h2     = (short*)(ws + 56033280);       // 6.4 MB

    prep_kernel<<<(N_NODES * IN_DIM / 4) / 256, 256, 0, stream>>>(x, xb, cnt, gcnt);
    hist_kernel<<<(N_EDGES + 255) / 256, 256, 0, stream>>>(dstp, cnt, N_EDGES);
    scan_kernel<<<(N_NODES + 255) / 256, 256, 0, stream>>>(cnt, offs, cursor, dis, gcnt, N_NODES);
    bucket_kernel<<<(N_EDGES + 255) / 256, 256, 0, stream>>>(srcp, dstp, cursor, ssrc, N_EDGES);
    pack_kernel<<<24, 256, 0, stream>>>(W1, W2, Bp1, Bp2);

    // layer 1: aggregate-first (bf16 gather), then MFMA GEMM (+bias+relu) -> bf16 h1
    agg1_kernel<<<(N_NODES + 3) / 4, 256, 0, stream>>>(xb, ssrc, offs, cnt, dis, aggx, N_NODES);
    gemm_mfma<IN_DIM, HID_DIM / 16, true, true>
        <<<(N_NODES + 63) / 64, 256, 0, stream>>>(aggx, Bp1, b1, h1, N_NODES, HID_DIM);

    // layer 2: transform-first MFMA GEMM -> bf16 h2, then fused aggregate+softmax
    gemm_mfma<HID_DIM, OUT_DIM / 16, true, false>
        <<<(N_NODES + 63) / 64, 256, 0, stream>>>(h1, Bp2, nullptr, h2, N_NODES, OUT_DIM);
    agg2_kernel<<<(N_NODES + 3) / 4, 256, 0, stream>>>(h2, ssrc, offs, cnt, dis, b2, out, N_NODES);
}

// Round 5
// 259.313 us; speedup vs baseline: 8.7295x; 1.0993x over previous
//
#include <hip/hip_runtime.h>
#include <hip/hip_bf16.h>
#include <math.h>

#define N_NODES 50000
#define N_EDGES 800000
#define IN_DIM 128
#define HID_DIM 256
#define OUT_DIM 64
#define NPART 196            // (N_NODES+255)/256 coarse buckets == scan blocks
#define CHUNK 2048           // edges per partition block
#define NPB ((N_EDGES + CHUNK - 1) / CHUNK)   // 391 partition blocks

typedef __attribute__((ext_vector_type(8))) short bf16x8;
typedef __attribute__((ext_vector_type(4))) short short4v;
typedef __attribute__((ext_vector_type(4))) float f32x4;

__device__ inline short f2bf(float f) {   // round-to-nearest-even bf16
    unsigned u = __float_as_uint(f);
    unsigned r = (u + 0x7fffu + ((u >> 16) & 1u)) >> 16;
    return (short)r;
}
__device__ inline float bf_lo(unsigned u) { return __uint_as_float(u << 16); }
__device__ inline float bf_hi(unsigned u) { return __uint_as_float(u & 0xffff0000u); }

// ---------------- prep: x -> bf16, zero cnt + global counter ----------------
__global__ void prep_kernel(const float* __restrict__ x, short* __restrict__ xb,
                            int* __restrict__ cnt, int* __restrict__ gcnt) {
    int idx = blockIdx.x * blockDim.x + threadIdx.x;   // exactly N_NODES*IN_DIM/4 threads
    float4 v = ((const float4*)x)[idx];
    short4v o = {f2bf(v.x), f2bf(v.y), f2bf(v.z), f2bf(v.w)};
    ((short4v*)xb)[idx] = o;
    if (idx < N_NODES) cnt[idx] = 0;
    if (idx == 0) *gcnt = 0;
}

// ---------------- histogram of dst ----------------
__global__ void hist_kernel(const int* __restrict__ dst, int* __restrict__ cnt, int E) {
    int e = blockIdx.x * blockDim.x + threadIdx.x;
    if (e < E) atomicAdd(&cnt[dst[e]], 1);
}

// ------- scan (blocks < NPART): block prefix + atomic base; also dis, coarse arrays ----
// ------- blocks >= NPART: pack W1/W2 into MFMA B-frag bf16 order ----------------------
__global__ __launch_bounds__(256) void scan_pack_kernel(const int* __restrict__ cnt,
                                                        int* __restrict__ offs,
                                                        float* __restrict__ dis,
                                                        int* __restrict__ gcnt,
                                                        int* __restrict__ coarseBase,
                                                        int* __restrict__ coarseCnt,
                                                        int* __restrict__ coarseCursor,
                                                        const float* __restrict__ W1,
                                                        const float* __restrict__ W2,
                                                        short* __restrict__ Bp1,
                                                        short* __restrict__ Bp2, int n) {
    if (blockIdx.x >= NPART) {
        // ---- pack path ----
        int idx = (blockIdx.x - NPART) * 256 + threadIdx.x;
        const float* W; short* Bp; int N;
        const int T1 = (IN_DIM / 32) * (HID_DIM / 16) * 64;    // 4096
        const int T2 = (HID_DIM / 32) * (OUT_DIM / 16) * 64;   // 2048
        if (idx < T1) { W = W1; Bp = Bp1; N = HID_DIM; }
        else { idx -= T1; if (idx >= T2) return; W = W2; Bp = Bp2; N = OUT_DIM; }
        int lane = idx & 63;
        int frag = idx >> 6;
        int ntiles = N >> 4;
        int nt = frag % ntiles;
        int kt = frag / ntiles;
        int col = nt * 16 + (lane & 15);
        int krow = kt * 32 + (lane >> 4) * 8;
        bf16x8 pk;
        #pragma unroll
        for (int j = 0; j < 8; j++) pk[j] = f2bf(W[(size_t)(krow + j) * N + col]);
        *((bf16x8*)(Bp + (size_t)idx * 8)) = pk;
        return;
    }
    __shared__ int ws[4];
    __shared__ int base;
    int tid = threadIdx.x, lane = tid & 63, wid = tid >> 6;
    int i = blockIdx.x * 256 + tid;
    int v = (i < n) ? cnt[i] : 0;
    int s = v;
    #pragma unroll
    for (int off = 1; off < 64; off <<= 1) {
        int t = __shfl_up(s, off, 64);
        if (lane >= off) s += t;
    }
    if (lane == 63) ws[wid] = s;
    __syncthreads();
    int wp = 0;
    #pragma unroll
    for (int w = 0; w < 4; w++) wp += (w < wid) ? ws[w] : 0;
    int excl = s - v + wp;
    if (tid == 255) {
        int total = excl + v;
        int b = atomicAdd(gcnt, total);
        base = b;
        coarseBase[blockIdx.x] = b;
        coarseCnt[blockIdx.x] = total;
        coarseCursor[blockIdx.x] = b;
    }
    __syncthreads();
    if (i < n) {
        offs[i] = base + excl;
        dis[i] = rsqrtf((float)v + 1.0f);   // +1 self-loop
    }
}

// ---------------- pass 1: LDS-staged coarse partition by dst>>8 ----------------
__global__ __launch_bounds__(256) void part1_kernel(const int* __restrict__ src,
                                                    const int* __restrict__ dst,
                                                    int* __restrict__ coarseCursor,
                                                    uint2* __restrict__ sedge, int E) {
    __shared__ int cnt_l[NPART];
    __shared__ int pref[NPART];
    __shared__ int gbase[NPART];
    __shared__ int ws4[4];
    __shared__ uint2 stage[CHUNK];
    int tid = threadIdx.x;
    int e0 = blockIdx.x * CHUNK;
    if (tid < NPART) cnt_l[tid] = 0;
    __syncthreads();
    int es[CHUNK / 256], ed[CHUNK / 256];
    #pragma unroll
    for (int j = 0; j < CHUNK / 256; j++) {
        int e = e0 + j * 256 + tid;
        if (e < E) {
            es[j] = src[e]; ed[j] = dst[e];
            atomicAdd(&cnt_l[ed[j] >> 8], 1);
        } else ed[j] = -1;
    }
    __syncthreads();
    // exclusive prefix over cnt_l
    int lane = tid & 63, wid = tid >> 6;
    int v = (tid < NPART) ? cnt_l[tid] : 0;
    int s = v;
    #pragma unroll
    for (int off = 1; off < 64; off <<= 1) {
        int t = __shfl_up(s, off, 64);
        if (lane >= off) s += t;
    }
    if (lane == 63) ws4[wid] = s;
    __syncthreads();
    int wp = 0;
    #pragma unroll
    for (int w = 0; w < 4; w++) wp += (w < wid) ? ws4[w] : 0;
    int excl = s - v + wp;
    if (tid < NPART) pref[tid] = excl;
    __syncthreads();
    if (tid < NPART) cnt_l[tid] = excl;   // reuse as local cursor
    __syncthreads();
    #pragma unroll
    for (int j = 0; j < CHUNK / 256; j++) {
        if (ed[j] >= 0) {
            int c = ed[j] >> 8;
            int p = atomicAdd(&cnt_l[c], 1);
            stage[p] = make_uint2((unsigned)es[j], (unsigned)ed[j]);
        }
    }
    __syncthreads();
    if (tid < NPART) {
        int cl = cnt_l[tid] - pref[tid];
        gbase[tid] = (cl > 0) ? atomicAdd(&coarseCursor[tid], cl) : 0;
    }
    __syncthreads();
    int total = (e0 + CHUNK <= E) ? CHUNK : (E - e0);
    for (int i = tid; i < total; i += 256) {
        uint2 ev = stage[i];
        int c = (int)(ev.y >> 8);
        sedge[gbase[c] + (i - pref[c])] = ev;
    }
}

// ---------------- pass 2: fine bucket within coarse region (LDS cursors) ----------------
__global__ __launch_bounds__(256) void part2_kernel(const uint2* __restrict__ sedge,
                                                    const int* __restrict__ coarseBase,
                                                    const int* __restrict__ coarseCnt,
                                                    const int* __restrict__ offs,
                                                    int* __restrict__ ssrc, int n) {
    __shared__ int cur[256];
    int b = blockIdx.x;
    int node0 = b * 256;
    int tid = threadIdx.x;
    if (node0 + tid < n) cur[tid] = offs[node0 + tid];
    __syncthreads();
    int base = coarseBase[b], cb = coarseCnt[b];
    for (int i = tid; i < cb; i += 256) {
        uint2 ev = sedge[base + i];
        int pos = atomicAdd(&cur[ev.y & 255], 1);
        ssrc[pos] = (int)ev.x;
    }
}

// ---------------- layer-1 aggregate: one wave per node, bf16 gather (256B rows) ------
__global__ void agg1_kernel(const short* __restrict__ xb, const int* __restrict__ ssrc,
                            const int* __restrict__ offs, const int* __restrict__ cnt,
                            const float* __restrict__ dis, short* __restrict__ aggx, int n) {
    int lane = threadIdx.x & 63;
    int node = blockIdx.x * (blockDim.x >> 6) + (threadIdx.x >> 6);
    if (node >= n) return;
    int grp = lane >> 4, l16 = lane & 15;
    int start = offs[node], c = cnt[node];
    float dn = dis[node];
    float acc[8] = {};
    for (int j = grp; j < c; j += 4) {
        int s = ssrc[start + j];
        float nm = dis[s] * dn;
        uint4 pk = *((const uint4*)(xb + (size_t)s * IN_DIM + l16 * 8));
        acc[0] += bf_lo(pk.x) * nm; acc[1] += bf_hi(pk.x) * nm;
        acc[2] += bf_lo(pk.y) * nm; acc[3] += bf_hi(pk.y) * nm;
        acc[4] += bf_lo(pk.z) * nm; acc[5] += bf_hi(pk.z) * nm;
        acc[6] += bf_lo(pk.w) * nm; acc[7] += bf_hi(pk.w) * nm;
    }
    #pragma unroll
    for (int k = 0; k < 8; k++) {
        acc[k] += __shfl_xor(acc[k], 16, 64);
        acc[k] += __shfl_xor(acc[k], 32, 64);
    }
    if (grp == 0) {
        float nm = dn * dn;
        uint4 pk = *((const uint4*)(xb + (size_t)node * IN_DIM + l16 * 8));
        acc[0] += bf_lo(pk.x) * nm; acc[1] += bf_hi(pk.x) * nm;
        acc[2] += bf_lo(pk.y) * nm; acc[3] += bf_hi(pk.y) * nm;
        acc[4] += bf_lo(pk.z) * nm; acc[5] += bf_hi(pk.z) * nm;
        acc[6] += bf_lo(pk.w) * nm; acc[7] += bf_hi(pk.w) * nm;
        bf16x8 o;
        #pragma unroll
        for (int k = 0; k < 8; k++) o[k] = f2bf(acc[k]);
        *((bf16x8*)(aggx + (size_t)node * IN_DIM + l16 * 8)) = o;
    }
}

// ---------------- LDS-free MFMA GEMM: C[M,N] = A[M,K](bf16) @ Bp(packed bf16) ----------
template <int K, int NT, bool OUT_BF16, bool RELU>
__global__ __launch_bounds__(256) void gemm_mfma(const short* __restrict__ A,
                                                 const short* __restrict__ Bp,
                                                 const float* __restrict__ bias,
                                                 void* __restrict__ C, int M, int N) {
    int lane = threadIdx.x & 63;
    int w = threadIdx.x >> 6;
    int rowBase = blockIdx.x * 64 + w * 16;
    int arow = rowBase + (lane & 15);
    int kseg = lane >> 4;             // 0..3
    f32x4 acc[NT] = {};
    constexpr int KT = K / 32;
    #pragma unroll
    for (int kt = 0; kt < KT; kt++) {
        bf16x8 a = {};
        if (arow < M)
            a = *((const bf16x8*)(A + (size_t)arow * K + kt * 32 + kseg * 8));
        #pragma unroll
        for (int nt = 0; nt < NT; nt++) {
            bf16x8 b = *((const bf16x8*)(Bp + ((size_t)(kt * NT + nt) * 64 + lane) * 8));
            acc[nt] = __builtin_amdgcn_mfma_f32_16x16x32_bf16(a, b, acc[nt], 0, 0, 0);
        }
    }
    // epilogue: C/D layout col=lane&15, row=(lane>>4)*4+i
    int col0 = lane & 15;
    #pragma unroll
    for (int nt = 0; nt < NT; nt++) {
        int col = nt * 16 + col0;
        float bv = RELU ? bias[col] : 0.0f;
        #pragma unroll
        for (int i = 0; i < 4; i++) {
            int r = rowBase + kseg * 4 + i;
            if (r >= M) continue;
            float v = acc[nt][i];
            if (RELU) { v += bv; v = fmaxf(v, 0.0f); }
            if (OUT_BF16) ((short*)C)[(size_t)r * N + col] = f2bf(v);
            else ((float*)C)[(size_t)r * N + col] = v;
        }
    }
}

// ---------------- layer-2 aggregate (bf16 gather) + self-loop + bias + log_softmax ----
__global__ void agg2_kernel(const short* __restrict__ h2, const int* __restrict__ ssrc,
                            const int* __restrict__ offs, const int* __restrict__ cnt,
                            const float* __restrict__ dis, const float* __restrict__ b2,
                            float* __restrict__ out, int n) {
    int lane = threadIdx.x & 63;
    int node = blockIdx.x * (blockDim.x >> 6) + (threadIdx.x >> 6);
    if (node >= n) return;
    int grp = lane >> 4, l16 = lane & 15;
    int start = offs[node], c = cnt[node];
    float dn = dis[node];
    float acc[4] = {};
    for (int j = grp; j < c; j += 4) {
        int s = ssrc[start + j];
        float nm = dis[s] * dn;
        uint2 pk = *((const uint2*)(h2 + (size_t)s * OUT_DIM + l16 * 4));
        acc[0] += bf_lo(pk.x) * nm; acc[1] += bf_hi(pk.x) * nm;
        acc[2] += bf_lo(pk.y) * nm; acc[3] += bf_hi(pk.y) * nm;
    }
    #pragma unroll
    for (int k = 0; k < 4; k++) {
        acc[k] += __shfl_xor(acc[k], 16, 64);
        acc[k] += __shfl_xor(acc[k], 32, 64);
    }
    float nm = dn * dn;
    uint2 pk = *((const uint2*)(h2 + (size_t)node * OUT_DIM + l16 * 4));
    float4 bb = ((const float4*)b2)[l16];
    acc[0] += bf_lo(pk.x) * nm + bb.x; acc[1] += bf_hi(pk.x) * nm + bb.y;
    acc[2] += bf_lo(pk.y) * nm + bb.z; acc[3] += bf_hi(pk.y) * nm + bb.w;
    float m = fmaxf(fmaxf(acc[0], acc[1]), fmaxf(acc[2], acc[3]));
    #pragma unroll
    for (int off = 1; off < 16; off <<= 1) m = fmaxf(m, __shfl_xor(m, off, 64));
    float ex = expf(acc[0] - m) + expf(acc[1] - m) + expf(acc[2] - m) + expf(acc[3] - m);
    #pragma unroll
    for (int off = 1; off < 16; off <<= 1) ex += __shfl_xor(ex, off, 64);
    float ls = m + logf(ex);
    if (grp == 0) {
        float4 o = {acc[0] - ls, acc[1] - ls, acc[2] - ls, acc[3] - ls};
        ((float4*)(out + (size_t)node * OUT_DIM))[l16] = o;
    }
}

extern "C" void kernel_launch(void* const* d_in, const int* in_sizes, int n_in,
                              void* d_out, int out_size, void* d_ws, size_t ws_size,
                              hipStream_t stream) {
    const float* x  = (const float*)d_in[0];
    const int*   ei = (const int*)d_in[1];
    const float* W1 = (const float*)d_in[2];
    const float* b1 = (const float*)d_in[3];
    const float* W2 = (const float*)d_in[4];
    const float* b2 = (const float*)d_in[5];
    float* out = (float*)d_out;
    char* ws = (char*)d_ws;

    const int* srcp = ei;
    const int* dstp = ei + N_EDGES;

    // workspace layout (256-aligned)
    int*   cnt    = (int*)(ws);                    // 50000 int
    int*   offs   = (int*)(ws + 262144);
    float* dis    = (float*)(ws + 524288);
    int*   gcnt   = (int*)(ws + 786432);
    int*   coarseBase   = (int*)(ws + 787456);     // 196 int
    int*   coarseCnt    = (int*)(ws + 788480);
    int*   coarseCursor = (int*)(ws + 789504);
    short* Bp1    = (short*)(ws + 1048576);        // 64 KB
    short* Bp2    = (short*)(ws + 1114112);        // 32 KB
    int*   ssrc   = (int*)(ws + 1179648);          // 3.2 MB, ends 4379648
    uint2* sedge  = (uint2*)(ws + 4456448);        // 6.4 MB staging (dead after part2)
    short* aggx   = (short*)(ws + 4456448);        // 12.8 MB, overlays sedge (live after part2)
    short* xb     = (short*)(ws + 17301504);       // 12.8 MB
    short* h1     = (short*)(ws + 30146560);       // 25.6 MB
    short* h2     = (short*)(ws + 55746560);       // 6.4 MB, ends ~62.1 MB

    prep_kernel<<<(N_NODES * IN_DIM / 4) / 256, 256, 0, stream>>>(x, xb, cnt, gcnt);
    hist_kernel<<<(N_EDGES + 255) / 256, 256, 0, stream>>>(dstp, cnt, N_EDGES);
    scan_pack_kernel<<<NPART + 24, 256, 0, stream>>>(cnt, offs, dis, gcnt,
                                                     coarseBase, coarseCnt, coarseCursor,
                                                     W1, W2, Bp1, Bp2, N_NODES);
    part1_kernel<<<NPB, 256, 0, stream>>>(srcp, dstp, coarseCursor, sedge, N_EDGES);
    part2_kernel<<<NPART, 256, 0, stream>>>(sedge, coarseBase, coarseCnt, offs, ssrc, N_NODES);

    // layer 1: aggregate-first (bf16 gather), then MFMA GEMM (+bias+relu) -> bf16 h1
    agg1_kernel<<<(N_NODES + 3) / 4, 256, 0, stream>>>(xb, ssrc, offs, cnt, dis, aggx, N_NODES);
    gemm_mfma<IN_DIM, HID_DIM / 16, true, true>
        <<<(N_NODES + 63) / 64, 256, 0, stream>>>(aggx, Bp1, b1, h1, N_NODES, HID_DIM);

    // layer 2: transform-first MFMA GEMM -> bf16 h2, then fused aggregate+softmax
    gemm_mfma<HID_DIM, OUT_DIM / 16, true, false>
        <<<(N_NODES + 63) / 64, 256, 0, stream>>>(h1, Bp2, nullptr, h2, N_NODES, OUT_DIM);
    agg2_kernel<<<(N_NODES + 3) / 4, 256, 0, stream>>>(h2, ssrc, offs, cnt, dis, b2, out, N_NODES);
}

// Round 6
// 243.664 us; speedup vs baseline: 9.2901x; 1.0642x over previous
//
#include <hip/hip_runtime.h>
#include <hip/hip_bf16.h>
#include <math.h>

#define N_NODES 50000
#define N_EDGES 800000
#define IN_DIM 128
#define HID_DIM 256
#define OUT_DIM 64
#define NPART 196            // (N_NODES+255)/256 coarse buckets == scan blocks
#define CHUNK 2048           // edges per partition block
#define NPB ((N_EDGES + CHUNK - 1) / CHUNK)   // 391 partition blocks
#define PREPB (N_NODES * IN_DIM / 4 / 256)    // 6250 prep blocks

typedef __attribute__((ext_vector_type(8))) short bf16x8;
typedef __attribute__((ext_vector_type(4))) short short4v;
typedef __attribute__((ext_vector_type(4))) float f32x4;

__device__ inline short f2bf(float f) {   // round-to-nearest-even bf16
    unsigned u = __float_as_uint(f);
    unsigned r = (u + 0x7fffu + ((u >> 16) & 1u)) >> 16;
    return (short)r;
}
__device__ inline float bf_lo(unsigned u) { return __uint_as_float(u << 16); }
__device__ inline float bf_hi(unsigned u) { return __uint_as_float(u & 0xffff0000u); }

// ---------------- histogram of dst ----------------
__global__ void hist_kernel(const int* __restrict__ dst, int* __restrict__ cnt, int E) {
    int e = blockIdx.x * blockDim.x + threadIdx.x;
    if (e < E) atomicAdd(&cnt[dst[e]], 1);
}

// ------- scan (blocks < NPART): block prefix + atomic base; also dis, coarse arrays ----
// ------- blocks >= NPART: pack W1/W2 into MFMA B-frag bf16 order ----------------------
__global__ __launch_bounds__(256) void scan_pack_kernel(const int* __restrict__ cnt,
                                                        int* __restrict__ offs,
                                                        float* __restrict__ dis,
                                                        int* __restrict__ gcnt,
                                                        int* __restrict__ coarseBase,
                                                        int* __restrict__ coarseCnt,
                                                        int* __restrict__ coarseCursor,
                                                        const float* __restrict__ W1,
                                                        const float* __restrict__ W2,
                                                        short* __restrict__ Bp1,
                                                        short* __restrict__ Bp2, int n) {
    if (blockIdx.x >= NPART) {
        // ---- pack path ----
        int idx = (blockIdx.x - NPART) * 256 + threadIdx.x;
        const float* W; short* Bp; int N;
        const int T1 = (IN_DIM / 32) * (HID_DIM / 16) * 64;    // 4096
        const int T2 = (HID_DIM / 32) * (OUT_DIM / 16) * 64;   // 2048
        if (idx < T1) { W = W1; Bp = Bp1; N = HID_DIM; }
        else { idx -= T1; if (idx >= T2) return; W = W2; Bp = Bp2; N = OUT_DIM; }
        int lane = idx & 63;
        int frag = idx >> 6;
        int ntiles = N >> 4;
        int nt = frag % ntiles;
        int kt = frag / ntiles;
        int col = nt * 16 + (lane & 15);
        int krow = kt * 32 + (lane >> 4) * 8;
        bf16x8 pk;
        #pragma unroll
        for (int j = 0; j < 8; j++) pk[j] = f2bf(W[(size_t)(krow + j) * N + col]);
        *((bf16x8*)(Bp + (size_t)idx * 8)) = pk;
        return;
    }
    __shared__ int ws[4];
    __shared__ int base;
    int tid = threadIdx.x, lane = tid & 63, wid = tid >> 6;
    int i = blockIdx.x * 256 + tid;
    int v = (i < n) ? cnt[i] : 0;
    int s = v;
    #pragma unroll
    for (int off = 1; off < 64; off <<= 1) {
        int t = __shfl_up(s, off, 64);
        if (lane >= off) s += t;
    }
    if (lane == 63) ws[wid] = s;
    __syncthreads();
    int wp = 0;
    #pragma unroll
    for (int w = 0; w < 4; w++) wp += (w < wid) ? ws[w] : 0;
    int excl = s - v + wp;
    if (tid == 255) {
        int total = excl + v;
        int b = atomicAdd(gcnt, total);
        base = b;
        coarseBase[blockIdx.x] = b;
        coarseCnt[blockIdx.x] = total;
        coarseCursor[blockIdx.x] = b;
    }
    __syncthreads();
    if (i < n) {
        offs[i] = base + excl;
        dis[i] = rsqrtf((float)v + 1.0f);   // +1 self-loop
    }
}

// ---- blocks < NPB: pass-1 LDS-staged coarse partition by dst>>8
// ---- blocks >= NPB: prep — xb[i,:] = bf16(x[i,:] * dis[i])  (pre-scaled by src norm)
__global__ __launch_bounds__(256) void part1_prep_kernel(const int* __restrict__ src,
                                                         const int* __restrict__ dst,
                                                         int* __restrict__ coarseCursor,
                                                         uint2* __restrict__ sedge,
                                                         const float* __restrict__ x,
                                                         const float* __restrict__ dis,
                                                         short* __restrict__ xb, int E) {
    __shared__ int cnt_l[NPART];
    __shared__ int pref[NPART];
    __shared__ int gbase[NPART];
    __shared__ int ws4[4];
    __shared__ uint2 stage[CHUNK];
    int tid = threadIdx.x;
    if (blockIdx.x >= NPB) {
        // ---- prep path: scaled bf16 conversion ----
        int idx = (blockIdx.x - NPB) * 256 + tid;          // < N_NODES*IN_DIM/4
        int node = idx >> 5;                               // 32 float4s per row
        float dn = dis[node];
        float4 v = ((const float4*)x)[idx];
        short4v o = {f2bf(v.x * dn), f2bf(v.y * dn), f2bf(v.z * dn), f2bf(v.w * dn)};
        ((short4v*)xb)[idx] = o;
        return;
    }
    int e0 = blockIdx.x * CHUNK;
    if (tid < NPART) cnt_l[tid] = 0;
    __syncthreads();
    int es[CHUNK / 256], ed[CHUNK / 256];
    #pragma unroll
    for (int j = 0; j < CHUNK / 256; j++) {
        int e = e0 + j * 256 + tid;
        if (e < E) {
            es[j] = src[e]; ed[j] = dst[e];
            atomicAdd(&cnt_l[ed[j] >> 8], 1);
        } else ed[j] = -1;
    }
    __syncthreads();
    int lane = tid & 63, wid = tid >> 6;
    int v = (tid < NPART) ? cnt_l[tid] : 0;
    int s = v;
    #pragma unroll
    for (int off = 1; off < 64; off <<= 1) {
        int t = __shfl_up(s, off, 64);
        if (lane >= off) s += t;
    }
    if (lane == 63) ws4[wid] = s;
    __syncthreads();
    int wp = 0;
    #pragma unroll
    for (int w = 0; w < 4; w++) wp += (w < wid) ? ws4[w] : 0;
    int excl = s - v + wp;
    if (tid < NPART) pref[tid] = excl;
    __syncthreads();
    if (tid < NPART) cnt_l[tid] = excl;   // reuse as local cursor
    __syncthreads();
    #pragma unroll
    for (int j = 0; j < CHUNK / 256; j++) {
        if (ed[j] >= 0) {
            int c = ed[j] >> 8;
            int p = atomicAdd(&cnt_l[c], 1);
            stage[p] = make_uint2((unsigned)es[j], (unsigned)ed[j]);
        }
    }
    __syncthreads();
    if (tid < NPART) {
        int cl = cnt_l[tid] - pref[tid];
        gbase[tid] = (cl > 0) ? atomicAdd(&coarseCursor[tid], cl) : 0;
    }
    __syncthreads();
    int total = (e0 + CHUNK <= E) ? CHUNK : (E - e0);
    for (int i = tid; i < total; i += 256) {
        uint2 ev = stage[i];
        int c = (int)(ev.y >> 8);
        sedge[gbase[c] + (i - pref[c])] = ev;
    }
}

// ---------------- pass 2: fine bucket within coarse region (LDS cursors) ----------------
__global__ __launch_bounds__(256) void part2_kernel(const uint2* __restrict__ sedge,
                                                    const int* __restrict__ coarseBase,
                                                    const int* __restrict__ coarseCnt,
                                                    const int* __restrict__ offs,
                                                    int* __restrict__ ssrc, int n) {
    __shared__ int cur[256];
    int b = blockIdx.x;
    int node0 = b * 256;
    int tid = threadIdx.x;
    if (node0 + tid < n) cur[tid] = offs[node0 + tid];
    __syncthreads();
    int base = coarseBase[b], cb = coarseCnt[b];
    for (int i = tid; i < cb; i += 256) {
        uint2 ev = sedge[base + i];
        int pos = atomicAdd(&cur[ev.y & 255], 1);
        ssrc[pos] = (int)ev.x;
    }
}

// ------- layer-1 aggregate: pre-scaled bf16 rows, pure sum, 2-edge unroll ----------
__global__ void agg1_kernel(const short* __restrict__ xb, const int* __restrict__ ssrc,
                            const int* __restrict__ offs, const int* __restrict__ cnt,
                            const float* __restrict__ dis, short* __restrict__ aggx, int n) {
    int lane = threadIdx.x & 63;
    int node = blockIdx.x * (blockDim.x >> 6) + (threadIdx.x >> 6);
    if (node >= n) return;
    int grp = lane >> 4, l16 = lane & 15;
    int start = offs[node], c = cnt[node];
    float acc[8] = {};
    int j = grp;
    for (; j + 4 < c; j += 8) {
        int s0 = ssrc[start + j];
        int s1 = ssrc[start + j + 4];
        uint4 p0 = *((const uint4*)(xb + (size_t)s0 * IN_DIM + l16 * 8));
        uint4 p1 = *((const uint4*)(xb + (size_t)s1 * IN_DIM + l16 * 8));
        acc[0] += bf_lo(p0.x); acc[1] += bf_hi(p0.x);
        acc[2] += bf_lo(p0.y); acc[3] += bf_hi(p0.y);
        acc[4] += bf_lo(p0.z); acc[5] += bf_hi(p0.z);
        acc[6] += bf_lo(p0.w); acc[7] += bf_hi(p0.w);
        acc[0] += bf_lo(p1.x); acc[1] += bf_hi(p1.x);
        acc[2] += bf_lo(p1.y); acc[3] += bf_hi(p1.y);
        acc[4] += bf_lo(p1.z); acc[5] += bf_hi(p1.z);
        acc[6] += bf_lo(p1.w); acc[7] += bf_hi(p1.w);
    }
    if (j < c) {
        int s0 = ssrc[start + j];
        uint4 p0 = *((const uint4*)(xb + (size_t)s0 * IN_DIM + l16 * 8));
        acc[0] += bf_lo(p0.x); acc[1] += bf_hi(p0.x);
        acc[2] += bf_lo(p0.y); acc[3] += bf_hi(p0.y);
        acc[4] += bf_lo(p0.z); acc[5] += bf_hi(p0.z);
        acc[6] += bf_lo(p0.w); acc[7] += bf_hi(p0.w);
    }
    #pragma unroll
    for (int k = 0; k < 8; k++) {
        acc[k] += __shfl_xor(acc[k], 16, 64);
        acc[k] += __shfl_xor(acc[k], 32, 64);
    }
    if (grp == 0) {
        float dn = dis[node];
        uint4 pk = *((const uint4*)(xb + (size_t)node * IN_DIM + l16 * 8));
        acc[0] += bf_lo(pk.x); acc[1] += bf_hi(pk.x);
        acc[2] += bf_lo(pk.y); acc[3] += bf_hi(pk.y);
        acc[4] += bf_lo(pk.z); acc[5] += bf_hi(pk.z);
        acc[6] += bf_lo(pk.w); acc[7] += bf_hi(pk.w);
        bf16x8 o;
        #pragma unroll
        for (int k = 0; k < 8; k++) o[k] = f2bf(acc[k] * dn);
        *((bf16x8*)(aggx + (size_t)node * IN_DIM + l16 * 8)) = o;
    }
}

// ---------------- LDS-free MFMA GEMM: C[M,N] = A[M,K](bf16) @ Bp(packed bf16) ----------
// SCALE: multiply output row r by scale[r] (layer-2: pre-scale h2 by dis)
template <int K, int NT, bool OUT_BF16, bool RELU, bool SCALE>
__global__ __launch_bounds__(256) void gemm_mfma(const short* __restrict__ A,
                                                 const short* __restrict__ Bp,
                                                 const float* __restrict__ bias,
                                                 const float* __restrict__ scale,
                                                 void* __restrict__ C, int M, int N) {
    int lane = threadIdx.x & 63;
    int w = threadIdx.x >> 6;
    int rowBase = blockIdx.x * 64 + w * 16;
    int arow = rowBase + (lane & 15);
    int kseg = lane >> 4;             // 0..3
    f32x4 acc[NT] = {};
    constexpr int KT = K / 32;
    #pragma unroll
    for (int kt = 0; kt < KT; kt++) {
        bf16x8 a = {};
        if (arow < M)
            a = *((const bf16x8*)(A + (size_t)arow * K + kt * 32 + kseg * 8));
        #pragma unroll
        for (int nt = 0; nt < NT; nt++) {
            bf16x8 b = *((const bf16x8*)(Bp + ((size_t)(kt * NT + nt) * 64 + lane) * 8));
            acc[nt] = __builtin_amdgcn_mfma_f32_16x16x32_bf16(a, b, acc[nt], 0, 0, 0);
        }
    }
    // epilogue: C/D layout col=lane&15, row=(lane>>4)*4+i
    int col0 = lane & 15;
    float sc[4];
    #pragma unroll
    for (int i = 0; i < 4; i++) {
        int r = rowBase + kseg * 4 + i;
        sc[i] = (SCALE && r < M) ? scale[r] : 1.0f;
    }
    #pragma unroll
    for (int nt = 0; nt < NT; nt++) {
        int col = nt * 16 + col0;
        float bv = RELU ? bias[col] : 0.0f;
        #pragma unroll
        for (int i = 0; i < 4; i++) {
            int r = rowBase + kseg * 4 + i;
            if (r >= M) continue;
            float v = acc[nt][i];
            if (RELU) { v += bv; v = fmaxf(v, 0.0f); }
            if (SCALE) v *= sc[i];
            if (OUT_BF16) ((short*)C)[(size_t)r * N + col] = f2bf(v);
            else ((float*)C)[(size_t)r * N + col] = v;
        }
    }
}

// ------- layer-2 aggregate: pre-scaled fp32 rows, pure sum, 2-edge unroll,
// ------- + self-loop + dn scale + bias + log_softmax fused ----------------
__global__ void agg2_kernel(const float* __restrict__ h2, const int* __restrict__ ssrc,
                            const int* __restrict__ offs, const int* __restrict__ cnt,
                            const float* __restrict__ dis, const float* __restrict__ b2,
                            float* __restrict__ out, int n) {
    int lane = threadIdx.x & 63;
    int node = blockIdx.x * (blockDim.x >> 6) + (threadIdx.x >> 6);
    if (node >= n) return;
    int grp = lane >> 4, l16 = lane & 15;
    int start = offs[node], c = cnt[node];
    float acc[4] = {};
    int j = grp;
    for (; j + 4 < c; j += 8) {
        int s0 = ssrc[start + j];
        int s1 = ssrc[start + j + 4];
        float4 v0 = ((const float4*)(h2 + (size_t)s0 * OUT_DIM))[l16];
        float4 v1 = ((const float4*)(h2 + (size_t)s1 * OUT_DIM))[l16];
        acc[0] += v0.x; acc[1] += v0.y; acc[2] += v0.z; acc[3] += v0.w;
        acc[0] += v1.x; acc[1] += v1.y; acc[2] += v1.z; acc[3] += v1.w;
    }
    if (j < c) {
        int s0 = ssrc[start + j];
        float4 v0 = ((const float4*)(h2 + (size_t)s0 * OUT_DIM))[l16];
        acc[0] += v0.x; acc[1] += v0.y; acc[2] += v0.z; acc[3] += v0.w;
    }
    #pragma unroll
    for (int k = 0; k < 4; k++) {
        acc[k] += __shfl_xor(acc[k], 16, 64);
        acc[k] += __shfl_xor(acc[k], 32, 64);
    }
    // self-loop + dn scale + bias
    float dn = dis[node];
    float4 v = ((const float4*)(h2 + (size_t)node * OUT_DIM))[l16];
    float4 bb = ((const float4*)b2)[l16];
    acc[0] = (acc[0] + v.x) * dn + bb.x; acc[1] = (acc[1] + v.y) * dn + bb.y;
    acc[2] = (acc[2] + v.z) * dn + bb.z; acc[3] = (acc[3] + v.w) * dn + bb.w;
    // log_softmax over 64 cols (16 l16-groups x 4 regs)
    float m = fmaxf(fmaxf(acc[0], acc[1]), fmaxf(acc[2], acc[3]));
    #pragma unroll
    for (int off = 1; off < 16; off <<= 1) m = fmaxf(m, __shfl_xor(m, off, 64));
    float ex = expf(acc[0] - m) + expf(acc[1] - m) + expf(acc[2] - m) + expf(acc[3] - m);
    #pragma unroll
    for (int off = 1; off < 16; off <<= 1) ex += __shfl_xor(ex, off, 64);
    float ls = m + logf(ex);
    if (grp == 0) {
        float4 o = {acc[0] - ls, acc[1] - ls, acc[2] - ls, acc[3] - ls};
        ((float4*)(out + (size_t)node * OUT_DIM))[l16] = o;
    }
}

extern "C" void kernel_launch(void* const* d_in, const int* in_sizes, int n_in,
                              void* d_out, int out_size, void* d_ws, size_t ws_size,
                              hipStream_t stream) {
    const float* x  = (const float*)d_in[0];
    const int*   ei = (const int*)d_in[1];
    const float* W1 = (const float*)d_in[2];
    const float* b1 = (const float*)d_in[3];
    const float* W2 = (const float*)d_in[4];
    const float* b2 = (const float*)d_in[5];
    float* out = (float*)d_out;
    char* ws = (char*)d_ws;

    const int* srcp = ei;
    const int* dstp = ei + N_EDGES;

    // workspace layout (256-aligned); cnt and gcnt adjacent for one memset
    int*   cnt    = (int*)(ws);                    // 50000 int
    int*   gcnt   = (int*)(ws + 200000);           // 1 int (memset with cnt)
    int*   offs   = (int*)(ws + 262144);
    float* dis    = (float*)(ws + 524288);
    int*   coarseBase   = (int*)(ws + 786432);     // 196 int
    int*   coarseCnt    = (int*)(ws + 787456);
    int*   coarseCursor = (int*)(ws + 788480);
    short* Bp1    = (short*)(ws + 1048576);        // 64 KB
    short* Bp2    = (short*)(ws + 1114112);        // 32 KB
    int*   ssrc   = (int*)(ws + 1179648);          // 3.2 MB
    uint2* sedge  = (uint2*)(ws + 4456448);        // 6.4 MB staging (dead after part2)
    short* aggx   = (short*)(ws + 4456448);        // 12.8 MB, overlays sedge
    short* xb     = (short*)(ws + 17301504);       // 12.8 MB
    short* h1     = (short*)(ws + 30146560);       // 25.6 MB
    float* h2     = (float*)(ws + 55746560);       // 12.8 MB fp32, ends ~68.5 MB

    hipMemsetAsync(cnt, 0, 200004, stream);        // cnt + gcnt

    hist_kernel<<<(N_EDGES + 255) / 256, 256, 0, stream>>>(dstp, cnt, N_EDGES);
    scan_pack_kernel<<<NPART + 24, 256, 0, stream>>>(cnt, offs, dis, gcnt,
                                                     coarseBase, coarseCnt, coarseCursor,
                                                     W1, W2, Bp1, Bp2, N_NODES);
    part1_prep_kernel<<<NPB + PREPB, 256, 0, stream>>>(srcp, dstp, coarseCursor, sedge,
                                                       x, dis, xb, N_EDGES);
    part2_kernel<<<NPART, 256, 0, stream>>>(sedge, coarseBase, coarseCnt, offs, ssrc, N_NODES);

    // layer 1: aggregate-first (pre-scaled bf16 gather), then MFMA GEMM (+bias+relu) -> bf16 h1
    agg1_kernel<<<(N_NODES + 3) / 4, 256, 0, stream>>>(xb, ssrc, offs, cnt, dis, aggx, N_NODES);
    gemm_mfma<IN_DIM, HID_DIM / 16, true, true, false>
        <<<(N_NODES + 63) / 64, 256, 0, stream>>>(aggx, Bp1, b1, nullptr, h1, N_NODES, HID_DIM);

    // layer 2: transform-first MFMA GEMM -> fp32 h2 pre-scaled by dis, then fused agg+softmax
    gemm_mfma<HID_DIM, OUT_DIM / 16, false, false, true>
        <<<(N_NODES + 63) / 64, 256, 0, stream>>>(h1, Bp2, nullptr, dis, h2, N_NODES, OUT_DIM);
    agg2_kernel<<<(N_NODES + 3) / 4, 256, 0, stream>>>(h2, ssrc, offs, cnt, dis, b2, out, N_NODES);
}

// Round 7
// 228.274 us; speedup vs baseline: 9.9164x; 1.0674x over previous
//
#include <hip/hip_runtime.h>
#include <hip/hip_bf16.h>
#include <math.h>

#define N_NODES 50000
#define N_EDGES 800000
#define IN_DIM 128
#define HID_DIM 256
#define OUT_DIM 64
#define NPART 196            // (N_NODES+255)/256 coarse buckets == scan blocks
#define CHUNK 2048           // edges per partition block
#define NPB ((N_EDGES + CHUNK - 1) / CHUNK)   // 391 partition blocks
#define PREPB (N_NODES * IN_DIM / 4 / 256)    // 6250 prep blocks

typedef __attribute__((ext_vector_type(8))) short bf16x8;
typedef __attribute__((ext_vector_type(4))) short short4v;
typedef __attribute__((ext_vector_type(4))) float f32x4;

__device__ inline short f2bf(float f) {   // round-to-nearest-even bf16
    unsigned u = __float_as_uint(f);
    unsigned r = (u + 0x7fffu + ((u >> 16) & 1u)) >> 16;
    return (short)r;
}
__device__ inline float bf_lo(unsigned u) { return __uint_as_float(u << 16); }
__device__ inline float bf_hi(unsigned u) { return __uint_as_float(u & 0xffff0000u); }

// ---------------- histogram of dst ----------------
__global__ void hist_kernel(const int* __restrict__ dst, int* __restrict__ cnt, int E) {
    int e = blockIdx.x * blockDim.x + threadIdx.x;
    if (e < E) atomicAdd(&cnt[dst[e]], 1);
}

// ------- scan (blocks < NPART): block prefix + atomic base; also dis, coarse arrays ----
// ------- blocks >= NPART: pack W1/W2 into MFMA B-frag bf16 order ----------------------
__global__ __launch_bounds__(256) void scan_pack_kernel(const int* __restrict__ cnt,
                                                        int* __restrict__ offs,
                                                        float* __restrict__ dis,
                                                        int* __restrict__ gcnt,
                                                        int* __restrict__ coarseBase,
                                                        int* __restrict__ coarseCnt,
                                                        int* __restrict__ coarseCursor,
                                                        const float* __restrict__ W1,
                                                        const float* __restrict__ W2,
                                                        short* __restrict__ Bp1,
                                                        short* __restrict__ Bp2, int n) {
    if (blockIdx.x >= NPART) {
        // ---- pack path ----
        int idx = (blockIdx.x - NPART) * 256 + threadIdx.x;
        const float* W; short* Bp; int N;
        const int T1 = (IN_DIM / 32) * (HID_DIM / 16) * 64;    // 4096
        const int T2 = (HID_DIM / 32) * (OUT_DIM / 16) * 64;   // 2048
        if (idx < T1) { W = W1; Bp = Bp1; N = HID_DIM; }
        else { idx -= T1; if (idx >= T2) return; W = W2; Bp = Bp2; N = OUT_DIM; }
        int lane = idx & 63;
        int frag = idx >> 6;
        int ntiles = N >> 4;
        int nt = frag % ntiles;
        int kt = frag / ntiles;
        int col = nt * 16 + (lane & 15);
        int krow = kt * 32 + (lane >> 4) * 8;
        bf16x8 pk;
        #pragma unroll
        for (int j = 0; j < 8; j++) pk[j] = f2bf(W[(size_t)(krow + j) * N + col]);
        *((bf16x8*)(Bp + (size_t)idx * 8)) = pk;
        return;
    }
    __shared__ int ws[4];
    __shared__ int base;
    int tid = threadIdx.x, lane = tid & 63, wid = tid >> 6;
    int i = blockIdx.x * 256 + tid;
    int v = (i < n) ? cnt[i] : 0;
    int s = v;
    #pragma unroll
    for (int off = 1; off < 64; off <<= 1) {
        int t = __shfl_up(s, off, 64);
        if (lane >= off) s += t;
    }
    if (lane == 63) ws[wid] = s;
    __syncthreads();
    int wp = 0;
    #pragma unroll
    for (int w = 0; w < 4; w++) wp += (w < wid) ? ws[w] : 0;
    int excl = s - v + wp;
    if (tid == 255) {
        int total = excl + v;
        int b = atomicAdd(gcnt, total);
        base = b;
        coarseBase[blockIdx.x] = b;
        coarseCnt[blockIdx.x] = total;
        coarseCursor[blockIdx.x] = b;
    }
    __syncthreads();
    if (i < n) {
        offs[i] = base + excl;
        dis[i] = rsqrtf((float)v + 1.0f);   // +1 self-loop
    }
}

// ---- blocks < NPB: pass-1 LDS-staged coarse partition by dst>>8
// ---- blocks >= NPB: prep — xb[i,:] = bf16(x[i,:] * dis[i])  (pre-scaled by src norm)
__global__ __launch_bounds__(256) void part1_prep_kernel(const int* __restrict__ src,
                                                         const int* __restrict__ dst,
                                                         int* __restrict__ coarseCursor,
                                                         uint2* __restrict__ sedge,
                                                         const float* __restrict__ x,
                                                         const float* __restrict__ dis,
                                                         short* __restrict__ xb, int E) {
    __shared__ int cnt_l[NPART];
    __shared__ int pref[NPART];
    __shared__ int gbase[NPART];
    __shared__ int ws4[4];
    __shared__ uint2 stage[CHUNK];
    int tid = threadIdx.x;
    if (blockIdx.x >= NPB) {
        // ---- prep path: scaled bf16 conversion ----
        int idx = (blockIdx.x - NPB) * 256 + tid;          // < N_NODES*IN_DIM/4
        int node = idx >> 5;                               // 32 float4s per row
        float dn = dis[node];
        float4 v = ((const float4*)x)[idx];
        short4v o = {f2bf(v.x * dn), f2bf(v.y * dn), f2bf(v.z * dn), f2bf(v.w * dn)};
        ((short4v*)xb)[idx] = o;
        return;
    }
    int e0 = blockIdx.x * CHUNK;
    if (tid < NPART) cnt_l[tid] = 0;
    __syncthreads();
    int es[CHUNK / 256], ed[CHUNK / 256];
    #pragma unroll
    for (int j = 0; j < CHUNK / 256; j++) {
        int e = e0 + j * 256 + tid;
        if (e < E) {
            es[j] = src[e]; ed[j] = dst[e];
            atomicAdd(&cnt_l[ed[j] >> 8], 1);
        } else ed[j] = -1;
    }
    __syncthreads();
    int lane = tid & 63, wid = tid >> 6;
    int v = (tid < NPART) ? cnt_l[tid] : 0;
    int s = v;
    #pragma unroll
    for (int off = 1; off < 64; off <<= 1) {
        int t = __shfl_up(s, off, 64);
        if (lane >= off) s += t;
    }
    if (lane == 63) ws4[wid] = s;
    __syncthreads();
    int wp = 0;
    #pragma unroll
    for (int w = 0; w < 4; w++) wp += (w < wid) ? ws4[w] : 0;
    int excl = s - v + wp;
    if (tid < NPART) pref[tid] = excl;
    __syncthreads();
    if (tid < NPART) cnt_l[tid] = excl;   // reuse as local cursor
    __syncthreads();
    #pragma unroll
    for (int j = 0; j < CHUNK / 256; j++) {
        if (ed[j] >= 0) {
            int c = ed[j] >> 8;
            int p = atomicAdd(&cnt_l[c], 1);
            stage[p] = make_uint2((unsigned)es[j], (unsigned)ed[j]);
        }
    }
    __syncthreads();
    if (tid < NPART) {
        int cl = cnt_l[tid] - pref[tid];
        gbase[tid] = (cl > 0) ? atomicAdd(&coarseCursor[tid], cl) : 0;
    }
    __syncthreads();
    int total = (e0 + CHUNK <= E) ? CHUNK : (E - e0);
    for (int i = tid; i < total; i += 256) {
        uint2 ev = stage[i];
        int c = (int)(ev.y >> 8);
        sedge[gbase[c] + (i - pref[c])] = ev;
    }
}

// ---------------- pass 2: fine bucket within coarse region (LDS cursors) ----------------
__global__ __launch_bounds__(256) void part2_kernel(const uint2* __restrict__ sedge,
                                                    const int* __restrict__ coarseBase,
                                                    const int* __restrict__ coarseCnt,
                                                    const int* __restrict__ offs,
                                                    int* __restrict__ ssrc, int n) {
    __shared__ int cur[256];
    int b = blockIdx.x;
    int node0 = b * 256;
    int tid = threadIdx.x;
    if (node0 + tid < n) cur[tid] = offs[node0 + tid];
    __syncthreads();
    int base = coarseBase[b], cb = coarseCnt[b];
    for (int i = tid; i < cb; i += 256) {
        uint2 ev = sedge[base + i];
        int pos = atomicAdd(&cur[ev.y & 255], 1);
        ssrc[pos] = (int)ev.x;
    }
}

// ------- layer-1 aggregate: pre-scaled bf16 rows, pure sum, 4-edge unroll ----------
__global__ void agg1_kernel(const short* __restrict__ xb, const int* __restrict__ ssrc,
                            const int* __restrict__ offs, const int* __restrict__ cnt,
                            const float* __restrict__ dis, short* __restrict__ aggx, int n) {
    int lane = threadIdx.x & 63;
    int node = blockIdx.x * (blockDim.x >> 6) + (threadIdx.x >> 6);
    if (node >= n) return;
    int grp = lane >> 4, l16 = lane & 15;
    int start = offs[node], c = cnt[node];
    float acc[8] = {};
    int j = grp;
    for (; j + 12 < c; j += 16) {
        int s0 = ssrc[start + j];
        int s1 = ssrc[start + j + 4];
        int s2 = ssrc[start + j + 8];
        int s3 = ssrc[start + j + 12];
        uint4 p0 = *((const uint4*)(xb + (size_t)s0 * IN_DIM + l16 * 8));
        uint4 p1 = *((const uint4*)(xb + (size_t)s1 * IN_DIM + l16 * 8));
        uint4 p2 = *((const uint4*)(xb + (size_t)s2 * IN_DIM + l16 * 8));
        uint4 p3 = *((const uint4*)(xb + (size_t)s3 * IN_DIM + l16 * 8));
        acc[0] += bf_lo(p0.x); acc[1] += bf_hi(p0.x); acc[2] += bf_lo(p0.y); acc[3] += bf_hi(p0.y);
        acc[4] += bf_lo(p0.z); acc[5] += bf_hi(p0.z); acc[6] += bf_lo(p0.w); acc[7] += bf_hi(p0.w);
        acc[0] += bf_lo(p1.x); acc[1] += bf_hi(p1.x); acc[2] += bf_lo(p1.y); acc[3] += bf_hi(p1.y);
        acc[4] += bf_lo(p1.z); acc[5] += bf_hi(p1.z); acc[6] += bf_lo(p1.w); acc[7] += bf_hi(p1.w);
        acc[0] += bf_lo(p2.x); acc[1] += bf_hi(p2.x); acc[2] += bf_lo(p2.y); acc[3] += bf_hi(p2.y);
        acc[4] += bf_lo(p2.z); acc[5] += bf_hi(p2.z); acc[6] += bf_lo(p2.w); acc[7] += bf_hi(p2.w);
        acc[0] += bf_lo(p3.x); acc[1] += bf_hi(p3.x); acc[2] += bf_lo(p3.y); acc[3] += bf_hi(p3.y);
        acc[4] += bf_lo(p3.z); acc[5] += bf_hi(p3.z); acc[6] += bf_lo(p3.w); acc[7] += bf_hi(p3.w);
    }
    for (; j < c; j += 4) {
        int s0 = ssrc[start + j];
        uint4 p0 = *((const uint4*)(xb + (size_t)s0 * IN_DIM + l16 * 8));
        acc[0] += bf_lo(p0.x); acc[1] += bf_hi(p0.x); acc[2] += bf_lo(p0.y); acc[3] += bf_hi(p0.y);
        acc[4] += bf_lo(p0.z); acc[5] += bf_hi(p0.z); acc[6] += bf_lo(p0.w); acc[7] += bf_hi(p0.w);
    }
    #pragma unroll
    for (int k = 0; k < 8; k++) {
        acc[k] += __shfl_xor(acc[k], 16, 64);
        acc[k] += __shfl_xor(acc[k], 32, 64);
    }
    if (grp == 0) {
        float dn = dis[node];
        uint4 pk = *((const uint4*)(xb + (size_t)node * IN_DIM + l16 * 8));
        acc[0] += bf_lo(pk.x); acc[1] += bf_hi(pk.x); acc[2] += bf_lo(pk.y); acc[3] += bf_hi(pk.y);
        acc[4] += bf_lo(pk.z); acc[5] += bf_hi(pk.z); acc[6] += bf_lo(pk.w); acc[7] += bf_hi(pk.w);
        bf16x8 o;
        #pragma unroll
        for (int k = 0; k < 8; k++) o[k] = f2bf(acc[k] * dn);
        *((bf16x8*)(aggx + (size_t)node * IN_DIM + l16 * 8)) = o;
    }
}

// -------- fused MFMA GEMM: h2[r,:] = dis[r] * (relu(aggx[r,:]@W1 + b1) @ W2) ----------
// 4 waves/block, each wave owns 16 rows. h1 tile round-trips through wave-private LDS
// (row stride 264 shorts = 528 B: 16B-aligned for ds_read_b128, 2-way bank alias = free).
#define H1_STRIDE 264
__global__ __launch_bounds__(256) void gemm_fused_kernel(const short* __restrict__ A,
                                                         const short* __restrict__ Bp1,
                                                         const short* __restrict__ Bp2,
                                                         const float* __restrict__ b1,
                                                         const float* __restrict__ dis,
                                                         short* __restrict__ h2, int M) {
    __shared__ short lds_h1[4][16][H1_STRIDE];
    int lane = threadIdx.x & 63;
    int w = threadIdx.x >> 6;
    int rowBase = blockIdx.x * 64 + w * 16;
    int arow = rowBase + (lane & 15);
    int kseg = lane >> 4;             // 0..3
    int col0 = lane & 15;

    // ---- phase A: h1 = relu(aggx @ W1 + b1), K=128, N=256 ----
    constexpr int NT1 = HID_DIM / 16;   // 16
    f32x4 acc1[NT1] = {};
    #pragma unroll
    for (int kt = 0; kt < IN_DIM / 32; kt++) {
        bf16x8 a = {};
        if (arow < M)
            a = *((const bf16x8*)(A + (size_t)arow * IN_DIM + kt * 32 + kseg * 8));
        #pragma unroll
        for (int nt = 0; nt < NT1; nt++) {
            bf16x8 b = *((const bf16x8*)(Bp1 + ((size_t)(kt * NT1 + nt) * 64 + lane) * 8));
            acc1[nt] = __builtin_amdgcn_mfma_f32_16x16x32_bf16(a, b, acc1[nt], 0, 0, 0);
        }
    }
    // C-layout (row=kseg*4+i, col=nt*16+col0) -> LDS as bf16
    #pragma unroll
    for (int nt = 0; nt < NT1; nt++) {
        float bv = b1[nt * 16 + col0];
        #pragma unroll
        for (int i = 0; i < 4; i++) {
            float v = fmaxf(acc1[nt][i] + bv, 0.0f);
            lds_h1[w][kseg * 4 + i][nt * 16 + col0] = f2bf(v);
        }
    }
    // ---- phase B: h2 = (h1 @ W2) * dis, K=256, N=64; A-frags from own wave's LDS ----
    constexpr int NT2 = OUT_DIM / 16;   // 4
    f32x4 acc2[NT2] = {};
    #pragma unroll
    for (int kt = 0; kt < HID_DIM / 32; kt++) {
        bf16x8 a = *((const bf16x8*)&lds_h1[w][lane & 15][kt * 32 + kseg * 8]);
        #pragma unroll
        for (int nt = 0; nt < NT2; nt++) {
            bf16x8 b = *((const bf16x8*)(Bp2 + ((size_t)(kt * NT2 + nt) * 64 + lane) * 8));
            acc2[nt] = __builtin_amdgcn_mfma_f32_16x16x32_bf16(a, b, acc2[nt], 0, 0, 0);
        }
    }
    #pragma unroll
    for (int i = 0; i < 4; i++) {
        int r = rowBase + kseg * 4 + i;
        if (r >= M) continue;
        float sc = dis[r];
        #pragma unroll
        for (int nt = 0; nt < NT2; nt++)
            h2[(size_t)r * OUT_DIM + nt * 16 + col0] = f2bf(acc2[nt][i] * sc);
    }
}

// ------- layer-2 aggregate: pre-scaled bf16 rows, pure sum, 4-edge unroll,
// ------- + self-loop + dn scale + bias + log_softmax fused ----------------
__global__ void agg2_kernel(const short* __restrict__ h2, const int* __restrict__ ssrc,
                            const int* __restrict__ offs, const int* __restrict__ cnt,
                            const float* __restrict__ dis, const float* __restrict__ b2,
                            float* __restrict__ out, int n) {
    int lane = threadIdx.x & 63;
    int node = blockIdx.x * (blockDim.x >> 6) + (threadIdx.x >> 6);
    if (node >= n) return;
    int grp = lane >> 4, l16 = lane & 15;
    int start = offs[node], c = cnt[node];
    float acc[4] = {};
    int j = grp;
    for (; j + 12 < c; j += 16) {
        int s0 = ssrc[start + j];
        int s1 = ssrc[start + j + 4];
        int s2 = ssrc[start + j + 8];
        int s3 = ssrc[start + j + 12];
        uint2 p0 = *((const uint2*)(h2 + (size_t)s0 * OUT_DIM + l16 * 4));
        uint2 p1 = *((const uint2*)(h2 + (size_t)s1 * OUT_DIM + l16 * 4));
        uint2 p2 = *((const uint2*)(h2 + (size_t)s2 * OUT_DIM + l16 * 4));
        uint2 p3 = *((const uint2*)(h2 + (size_t)s3 * OUT_DIM + l16 * 4));
        acc[0] += bf_lo(p0.x); acc[1] += bf_hi(p0.x); acc[2] += bf_lo(p0.y); acc[3] += bf_hi(p0.y);
        acc[0] += bf_lo(p1.x); acc[1] += bf_hi(p1.x); acc[2] += bf_lo(p1.y); acc[3] += bf_hi(p1.y);
        acc[0] += bf_lo(p2.x); acc[1] += bf_hi(p2.x); acc[2] += bf_lo(p2.y); acc[3] += bf_hi(p2.y);
        acc[0] += bf_lo(p3.x); acc[1] += bf_hi(p3.x); acc[2] += bf_lo(p3.y); acc[3] += bf_hi(p3.y);
    }
    for (; j < c; j += 4) {
        int s0 = ssrc[start + j];
        uint2 p0 = *((const uint2*)(h2 + (size_t)s0 * OUT_DIM + l16 * 4));
        acc[0] += bf_lo(p0.x); acc[1] += bf_hi(p0.x); acc[2] += bf_lo(p0.y); acc[3] += bf_hi(p0.y);
    }
    #pragma unroll
    for (int k = 0; k < 4; k++) {
        acc[k] += __shfl_xor(acc[k], 16, 64);
        acc[k] += __shfl_xor(acc[k], 32, 64);
    }
    // self-loop + dn scale + bias
    float dn = dis[node];
    uint2 pv = *((const uint2*)(h2 + (size_t)node * OUT_DIM + l16 * 4));
    float4 bb = ((const float4*)b2)[l16];
    acc[0] = (acc[0] + bf_lo(pv.x)) * dn + bb.x;
    acc[1] = (acc[1] + bf_hi(pv.x)) * dn + bb.y;
    acc[2] = (acc[2] + bf_lo(pv.y)) * dn + bb.z;
    acc[3] = (acc[3] + bf_hi(pv.y)) * dn + bb.w;
    // log_softmax over 64 cols (16 l16-groups x 4 regs)
    float m = fmaxf(fmaxf(acc[0], acc[1]), fmaxf(acc[2], acc[3]));
    #pragma unroll
    for (int off = 1; off < 16; off <<= 1) m = fmaxf(m, __shfl_xor(m, off, 64));
    float ex = expf(acc[0] - m) + expf(acc[1] - m) + expf(acc[2] - m) + expf(acc[3] - m);
    #pragma unroll
    for (int off = 1; off < 16; off <<= 1) ex += __shfl_xor(ex, off, 64);
    float ls = m + logf(ex);
    if (grp == 0) {
        float4 o = {acc[0] - ls, acc[1] - ls, acc[2] - ls, acc[3] - ls};
        ((float4*)(out + (size_t)node * OUT_DIM))[l16] = o;
    }
}

extern "C" void kernel_launch(void* const* d_in, const int* in_sizes, int n_in,
                              void* d_out, int out_size, void* d_ws, size_t ws_size,
                              hipStream_t stream) {
    const float* x  = (const float*)d_in[0];
    const int*   ei = (const int*)d_in[1];
    const float* W1 = (const float*)d_in[2];
    const float* b1 = (const float*)d_in[3];
    const float* W2 = (const float*)d_in[4];
    const float* b2 = (const float*)d_in[5];
    float* out = (float*)d_out;
    char* ws = (char*)d_ws;

    const int* srcp = ei;
    const int* dstp = ei + N_EDGES;

    // workspace layout (256-aligned); cnt and gcnt adjacent for one memset
    int*   cnt    = (int*)(ws);                    // 50000 int
    int*   gcnt   = (int*)(ws + 200000);           // 1 int (memset with cnt)
    int*   offs   = (int*)(ws + 262144);
    float* dis    = (float*)(ws + 524288);
    int*   coarseBase   = (int*)(ws + 786432);     // 196 int
    int*   coarseCnt    = (int*)(ws + 787456);
    int*   coarseCursor = (int*)(ws + 788480);
    short* Bp1    = (short*)(ws + 1048576);        // 64 KB
    short* Bp2    = (short*)(ws + 1114112);        // 32 KB
    int*   ssrc   = (int*)(ws + 1179648);          // 3.2 MB
    uint2* sedge  = (uint2*)(ws + 4456448);        // 6.4 MB staging (dead after part2)
    short* aggx   = (short*)(ws + 4456448);        // 12.8 MB, overlays sedge
    short* xb     = (short*)(ws + 17301504);       // 12.8 MB
    short* h2     = (short*)(ws + 30146560);       // 6.4 MB bf16, ends ~36.5 MB

    hipMemsetAsync(cnt, 0, 200004, stream);        // cnt + gcnt

    hist_kernel<<<(N_EDGES + 255) / 256, 256, 0, stream>>>(dstp, cnt, N_EDGES);
    scan_pack_kernel<<<NPART + 24, 256, 0, stream>>>(cnt, offs, dis, gcnt,
                                                     coarseBase, coarseCnt, coarseCursor,
                                                     W1, W2, Bp1, Bp2, N_NODES);
    part1_prep_kernel<<<NPB + PREPB, 256, 0, stream>>>(srcp, dstp, coarseCursor, sedge,
                                                       x, dis, xb, N_EDGES);
    part2_kernel<<<NPART, 256, 0, stream>>>(sedge, coarseBase, coarseCnt, offs, ssrc, N_NODES);

    // layer 1 aggregate, then fused GEMM (L1 + relu + L2 + dis scale) -> bf16 h2
    agg1_kernel<<<(N_NODES + 3) / 4, 256, 0, stream>>>(xb, ssrc, offs, cnt, dis, aggx, N_NODES);
    gemm_fused_kernel<<<(N_NODES + 63) / 64, 256, 0, stream>>>(aggx, Bp1, Bp2, b1, dis,
                                                               h2, N_NODES);
    agg2_kernel<<<(N_NODES + 3) / 4, 256, 0, stream>>>(h2, ssrc, offs, cnt, dis, b2, out, N_NODES);
}

// Round 8
// 206.182 us; speedup vs baseline: 10.9789x; 1.1071x over previous
//
#include <hip/hip_runtime.h>
#include <hip/hip_bf16.h>
#include <math.h>

#define N_NODES 50000
#define N_EDGES 800000
#define IN_DIM 128
#define HID_DIM 256
#define OUT_DIM 64
#define NPART 196            // ceil(N_NODES/256) coarse buckets
#define CAP 8192             // static per-bucket capacity (mean 4096, sigma 64)
#define CHUNK 2048           // edges per partition block
#define NPB ((N_EDGES + CHUNK - 1) / CHUNK)   // 391 partition blocks

typedef __attribute__((ext_vector_type(8))) short bf16x8;
typedef __attribute__((ext_vector_type(4))) short short4v;
typedef __attribute__((ext_vector_type(4))) float f32x4;

__device__ inline short f2bf(float f) {   // round-to-nearest-even bf16
    unsigned u = __float_as_uint(f);
    unsigned r = (u + 0x7fffu + ((u >> 16) & 1u)) >> 16;
    return (short)r;
}
__device__ inline float bf_lo(unsigned u) { return __uint_as_float(u << 16); }
__device__ inline float bf_hi(unsigned u) { return __uint_as_float(u & 0xffff0000u); }

// ---- blocks < NPB: pass-1 LDS-staged coarse partition by dst>>8 into static slots
// ---- blocks >= NPB: pack W1/W2 into MFMA B-frag bf16 order
__global__ __launch_bounds__(256) void part1_pack_kernel(const int* __restrict__ src,
                                                         const int* __restrict__ dst,
                                                         int* __restrict__ coarseCursor,
                                                         uint2* __restrict__ sedge,
                                                         const float* __restrict__ W1,
                                                         const float* __restrict__ W2,
                                                         short* __restrict__ Bp1,
                                                         short* __restrict__ Bp2, int E) {
    __shared__ int cnt_l[NPART];
    __shared__ int pref[NPART];
    __shared__ int gbase[NPART];
    __shared__ int ws4[4];
    __shared__ uint2 stage[CHUNK];
    int tid = threadIdx.x;
    if (blockIdx.x >= NPB) {
        // ---- pack path ----
        int idx = (blockIdx.x - NPB) * 256 + tid;
        const float* W; short* Bp; int N;
        const int T1 = (IN_DIM / 32) * (HID_DIM / 16) * 64;    // 4096
        const int T2 = (HID_DIM / 32) * (OUT_DIM / 16) * 64;   // 2048
        if (idx < T1) { W = W1; Bp = Bp1; N = HID_DIM; }
        else { idx -= T1; if (idx >= T2) return; W = W2; Bp = Bp2; N = OUT_DIM; }
        int lane = idx & 63;
        int frag = idx >> 6;
        int ntiles = N >> 4;
        int nt = frag % ntiles;
        int kt = frag / ntiles;
        int col = nt * 16 + (lane & 15);
        int krow = kt * 32 + (lane >> 4) * 8;
        bf16x8 pk;
        #pragma unroll
        for (int j = 0; j < 8; j++) pk[j] = f2bf(W[(size_t)(krow + j) * N + col]);
        *((bf16x8*)(Bp + (size_t)idx * 8)) = pk;
        return;
    }
    int e0 = blockIdx.x * CHUNK;
    if (tid < NPART) cnt_l[tid] = 0;
    __syncthreads();
    int es[CHUNK / 256], ed[CHUNK / 256];
    #pragma unroll
    for (int j = 0; j < CHUNK / 256; j++) {
        int e = e0 + j * 256 + tid;
        if (e < E) {
            es[j] = src[e]; ed[j] = dst[e];
            atomicAdd(&cnt_l[ed[j] >> 8], 1);
        } else ed[j] = -1;
    }
    __syncthreads();
    int lane = tid & 63, wid = tid >> 6;
    int v = (tid < NPART) ? cnt_l[tid] : 0;
    int s = v;
    #pragma unroll
    for (int off = 1; off < 64; off <<= 1) {
        int t = __shfl_up(s, off, 64);
        if (lane >= off) s += t;
    }
    if (lane == 63) ws4[wid] = s;
    __syncthreads();
    int wp = 0;
    #pragma unroll
    for (int w = 0; w < 4; w++) wp += (w < wid) ? ws4[w] : 0;
    int excl = s - v + wp;
    if (tid < NPART) pref[tid] = excl;
    __syncthreads();
    if (tid < NPART) cnt_l[tid] = excl;   // reuse as local cursor
    __syncthreads();
    #pragma unroll
    for (int j = 0; j < CHUNK / 256; j++) {
        if (ed[j] >= 0) {
            int c = ed[j] >> 8;
            int p = atomicAdd(&cnt_l[c], 1);
            stage[p] = make_uint2((unsigned)es[j], (unsigned)ed[j]);
        }
    }
    __syncthreads();
    if (tid < NPART) {
        int cl = cnt_l[tid] - pref[tid];
        gbase[tid] = (cl > 0) ? (tid * CAP + atomicAdd(&coarseCursor[tid], cl)) : 0;
    }
    __syncthreads();
    int total = (e0 + CHUNK <= E) ? CHUNK : (E - e0);
    for (int i = tid; i < total; i += 256) {
        uint2 ev = stage[i];
        int c = (int)(ev.y >> 8);
        sedge[gbase[c] + (i - pref[c])] = ev;
    }
}

// ---- pass 2 (one block per coarse bucket): local per-node count + scan -> offs/cnt/dis,
// ---- fine scatter with LDS cursors, then prep xb rows for this block's own 256 nodes.
__global__ __launch_bounds__(256) void part2_kernel(const uint2* __restrict__ sedge,
                                                    const int* __restrict__ coarseCnt,
                                                    int* __restrict__ offs,
                                                    int* __restrict__ cntg,
                                                    float* __restrict__ dis,
                                                    int* __restrict__ ssrc,
                                                    const float* __restrict__ x,
                                                    short* __restrict__ xb, int n) {
    __shared__ int kcnt[256];
    __shared__ int ws4[4];
    __shared__ float sdis[256];
    int b = blockIdx.x, tid = threadIdx.x;
    int base = b * CAP;
    int cb = coarseCnt[b];
    kcnt[tid] = 0;
    __syncthreads();
    for (int i = tid; i < cb; i += 256) {
        uint2 ev = sedge[base + i];
        atomicAdd(&kcnt[ev.y & 255], 1);
    }
    __syncthreads();
    int v = kcnt[tid];
    int lane = tid & 63, wid = tid >> 6;
    int s = v;
    #pragma unroll
    for (int off = 1; off < 64; off <<= 1) {
        int t = __shfl_up(s, off, 64);
        if (lane >= off) s += t;
    }
    if (lane == 63) ws4[wid] = s;
    __syncthreads();
    int wp = 0;
    #pragma unroll
    for (int w = 0; w < 4; w++) wp += (w < wid) ? ws4[w] : 0;
    int excl = s - v + wp;
    int node = b * 256 + tid;
    float dn = rsqrtf((float)v + 1.0f);   // +1 self-loop
    if (node < n) {
        offs[node] = base + excl;
        cntg[node] = v;
        dis[node] = dn;
    }
    sdis[tid] = dn;
    __syncthreads();
    kcnt[tid] = base + excl;              // becomes cursor
    __syncthreads();
    for (int i = tid; i < cb; i += 256) {
        uint2 ev = sedge[base + i];
        int pos = atomicAdd(&kcnt[ev.y & 255], 1);
        ssrc[pos] = (int)ev.x;
    }
    // prep: xb[nd,:] = bf16(x[nd,:] * dis[nd]) for this block's nodes, coalesced
    int rlane = tid & 31, rgrp = tid >> 5;
    for (int rb = 0; rb < 32; rb++) {
        int row = rb * 8 + rgrp;
        int nd = b * 256 + row;
        if (nd >= n) break;
        float d2 = sdis[row];
        float4 vv = ((const float4*)(x + (size_t)nd * IN_DIM))[rlane];
        short4v o = {f2bf(vv.x * d2), f2bf(vv.y * d2), f2bf(vv.z * d2), f2bf(vv.w * d2)};
        *((short4v*)(xb + (size_t)nd * IN_DIM + rlane * 4)) = o;
    }
}

// ------- layer-1 aggregate: pre-scaled bf16 rows, pure sum, 4-edge unroll ----------
__global__ void agg1_kernel(const short* __restrict__ xb, const int* __restrict__ ssrc,
                            const int* __restrict__ offs, const int* __restrict__ cnt,
                            const float* __restrict__ dis, short* __restrict__ aggx, int n) {
    int lane = threadIdx.x & 63;
    int node = blockIdx.x * (blockDim.x >> 6) + (threadIdx.x >> 6);
    if (node >= n) return;
    int grp = lane >> 4, l16 = lane & 15;
    int start = offs[node], c = cnt[node];
    float acc[8] = {};
    int j = grp;
    for (; j + 12 < c; j += 16) {
        int s0 = ssrc[start + j];
        int s1 = ssrc[start + j + 4];
        int s2 = ssrc[start + j + 8];
        int s3 = ssrc[start + j + 12];
        uint4 p0 = *((const uint4*)(xb + (size_t)s0 * IN_DIM + l16 * 8));
        uint4 p1 = *((const uint4*)(xb + (size_t)s1 * IN_DIM + l16 * 8));
        uint4 p2 = *((const uint4*)(xb + (size_t)s2 * IN_DIM + l16 * 8));
        uint4 p3 = *((const uint4*)(xb + (size_t)s3 * IN_DIM + l16 * 8));
        acc[0] += bf_lo(p0.x); acc[1] += bf_hi(p0.x); acc[2] += bf_lo(p0.y); acc[3] += bf_hi(p0.y);
        acc[4] += bf_lo(p0.z); acc[5] += bf_hi(p0.z); acc[6] += bf_lo(p0.w); acc[7] += bf_hi(p0.w);
        acc[0] += bf_lo(p1.x); acc[1] += bf_hi(p1.x); acc[2] += bf_lo(p1.y); acc[3] += bf_hi(p1.y);
        acc[4] += bf_lo(p1.z); acc[5] += bf_hi(p1.z); acc[6] += bf_lo(p1.w); acc[7] += bf_hi(p1.w);
        acc[0] += bf_lo(p2.x); acc[1] += bf_hi(p2.x); acc[2] += bf_lo(p2.y); acc[3] += bf_hi(p2.y);
        acc[4] += bf_lo(p2.z); acc[5] += bf_hi(p2.z); acc[6] += bf_lo(p2.w); acc[7] += bf_hi(p2.w);
        acc[0] += bf_lo(p3.x); acc[1] += bf_hi(p3.x); acc[2] += bf_lo(p3.y); acc[3] += bf_hi(p3.y);
        acc[4] += bf_lo(p3.z); acc[5] += bf_hi(p3.z); acc[6] += bf_lo(p3.w); acc[7] += bf_hi(p3.w);
    }
    for (; j < c; j += 4) {
        int s0 = ssrc[start + j];
        uint4 p0 = *((const uint4*)(xb + (size_t)s0 * IN_DIM + l16 * 8));
        acc[0] += bf_lo(p0.x); acc[1] += bf_hi(p0.x); acc[2] += bf_lo(p0.y); acc[3] += bf_hi(p0.y);
        acc[4] += bf_lo(p0.z); acc[5] += bf_hi(p0.z); acc[6] += bf_lo(p0.w); acc[7] += bf_hi(p0.w);
    }
    #pragma unroll
    for (int k = 0; k < 8; k++) {
        acc[k] += __shfl_xor(acc[k], 16, 64);
        acc[k] += __shfl_xor(acc[k], 32, 64);
    }
    if (grp == 0) {
        float dn = dis[node];
        uint4 pk = *((const uint4*)(xb + (size_t)node * IN_DIM + l16 * 8));
        acc[0] += bf_lo(pk.x); acc[1] += bf_hi(pk.x); acc[2] += bf_lo(pk.y); acc[3] += bf_hi(pk.y);
        acc[4] += bf_lo(pk.z); acc[5] += bf_hi(pk.z); acc[6] += bf_lo(pk.w); acc[7] += bf_hi(pk.w);
        bf16x8 o;
        #pragma unroll
        for (int k = 0; k < 8; k++) o[k] = f2bf(acc[k] * dn);
        *((bf16x8*)(aggx + (size_t)node * IN_DIM + l16 * 8)) = o;
    }
}

// -------- fused MFMA GEMM: h2[r,:] = dis[r] * (relu(aggx[r,:]@W1 + b1) @ W2) ----------
#define H1_STRIDE 264
__global__ __launch_bounds__(256) void gemm_fused_kernel(const short* __restrict__ A,
                                                         const short* __restrict__ Bp1,
                                                         const short* __restrict__ Bp2,
                                                         const float* __restrict__ b1,
                                                         const float* __restrict__ dis,
                                                         short* __restrict__ h2, int M) {
    __shared__ short lds_h1[4][16][H1_STRIDE];
    int lane = threadIdx.x & 63;
    int w = threadIdx.x >> 6;
    int rowBase = blockIdx.x * 64 + w * 16;
    int arow = rowBase + (lane & 15);
    int kseg = lane >> 4;             // 0..3
    int col0 = lane & 15;

    // ---- phase A: h1 = relu(aggx @ W1 + b1), K=128, N=256 ----
    constexpr int NT1 = HID_DIM / 16;   // 16
    f32x4 acc1[NT1] = {};
    #pragma unroll
    for (int kt = 0; kt < IN_DIM / 32; kt++) {
        bf16x8 a = {};
        if (arow < M)
            a = *((const bf16x8*)(A + (size_t)arow * IN_DIM + kt * 32 + kseg * 8));
        #pragma unroll
        for (int nt = 0; nt < NT1; nt++) {
            bf16x8 b = *((const bf16x8*)(Bp1 + ((size_t)(kt * NT1 + nt) * 64 + lane) * 8));
            acc1[nt] = __builtin_amdgcn_mfma_f32_16x16x32_bf16(a, b, acc1[nt], 0, 0, 0);
        }
    }
    #pragma unroll
    for (int nt = 0; nt < NT1; nt++) {
        float bv = b1[nt * 16 + col0];
        #pragma unroll
        for (int i = 0; i < 4; i++) {
            float v = fmaxf(acc1[nt][i] + bv, 0.0f);
            lds_h1[w][kseg * 4 + i][nt * 16 + col0] = f2bf(v);
        }
    }
    // ---- phase B: h2 = (h1 @ W2) * dis, K=256, N=64; A-frags from own wave's LDS ----
    constexpr int NT2 = OUT_DIM / 16;   // 4
    f32x4 acc2[NT2] = {};
    #pragma unroll
    for (int kt = 0; kt < HID_DIM / 32; kt++) {
        bf16x8 a = *((const bf16x8*)&lds_h1[w][lane & 15][kt * 32 + kseg * 8]);
        #pragma unroll
        for (int nt = 0; nt < NT2; nt++) {
            bf16x8 b = *((const bf16x8*)(Bp2 + ((size_t)(kt * NT2 + nt) * 64 + lane) * 8));
            acc2[nt] = __builtin_amdgcn_mfma_f32_16x16x32_bf16(a, b, acc2[nt], 0, 0, 0);
        }
    }
    #pragma unroll
    for (int i = 0; i < 4; i++) {
        int r = rowBase + kseg * 4 + i;
        if (r >= M) continue;
        float sc = dis[r];
        #pragma unroll
        for (int nt = 0; nt < NT2; nt++)
            h2[(size_t)r * OUT_DIM + nt * 16 + col0] = f2bf(acc2[nt][i] * sc);
    }
}

// ------- layer-2 aggregate: pre-scaled bf16 rows, pure sum, 4-edge unroll,
// ------- + self-loop + dn scale + bias + log_softmax fused ----------------
__global__ void agg2_kernel(const short* __restrict__ h2, const int* __restrict__ ssrc,
                            const int* __restrict__ offs, const int* __restrict__ cnt,
                            const float* __restrict__ dis, const float* __restrict__ b2,
                            float* __restrict__ out, int n) {
    int lane = threadIdx.x & 63;
    int node = blockIdx.x * (blockDim.x >> 6) + (threadIdx.x >> 6);
    if (node >= n) return;
    int grp = lane >> 4, l16 = lane & 15;
    int start = offs[node], c = cnt[node];
    float acc[4] = {};
    int j = grp;
    for (; j + 12 < c; j += 16) {
        int s0 = ssrc[start + j];
        int s1 = ssrc[start + j + 4];
        int s2 = ssrc[start + j + 8];
        int s3 = ssrc[start + j + 12];
        uint2 p0 = *((const uint2*)(h2 + (size_t)s0 * OUT_DIM + l16 * 4));
        uint2 p1 = *((const uint2*)(h2 + (size_t)s1 * OUT_DIM + l16 * 4));
        uint2 p2 = *((const uint2*)(h2 + (size_t)s2 * OUT_DIM + l16 * 4));
        uint2 p3 = *((const uint2*)(h2 + (size_t)s3 * OUT_DIM + l16 * 4));
        acc[0] += bf_lo(p0.x); acc[1] += bf_hi(p0.x); acc[2] += bf_lo(p0.y); acc[3] += bf_hi(p0.y);
        acc[0] += bf_lo(p1.x); acc[1] += bf_hi(p1.x); acc[2] += bf_lo(p1.y); acc[3] += bf_hi(p1.y);
        acc[0] += bf_lo(p2.x); acc[1] += bf_hi(p2.x); acc[2] += bf_lo(p2.y); acc[3] += bf_hi(p2.y);
        acc[0] += bf_lo(p3.x); acc[1] += bf_hi(p3.x); acc[2] += bf_lo(p3.y); acc[3] += bf_hi(p3.y);
    }
    for (; j < c; j += 4) {
        int s0 = ssrc[start + j];
        uint2 p0 = *((const uint2*)(h2 + (size_t)s0 * OUT_DIM + l16 * 4));
        acc[0] += bf_lo(p0.x); acc[1] += bf_hi(p0.x); acc[2] += bf_lo(p0.y); acc[3] += bf_hi(p0.y);
    }
    #pragma unroll
    for (int k = 0; k < 4; k++) {
        acc[k] += __shfl_xor(acc[k], 16, 64);
        acc[k] += __shfl_xor(acc[k], 32, 64);
    }
    float dn = dis[node];
    uint2 pv = *((const uint2*)(h2 + (size_t)node * OUT_DIM + l16 * 4));
    float4 bb = ((const float4*)b2)[l16];
    acc[0] = (acc[0] + bf_lo(pv.x)) * dn + bb.x;
    acc[1] = (acc[1] + bf_hi(pv.x)) * dn + bb.y;
    acc[2] = (acc[2] + bf_lo(pv.y)) * dn + bb.z;
    acc[3] = (acc[3] + bf_hi(pv.y)) * dn + bb.w;
    float m = fmaxf(fmaxf(acc[0], acc[1]), fmaxf(acc[2], acc[3]));
    #pragma unroll
    for (int off = 1; off < 16; off <<= 1) m = fmaxf(m, __shfl_xor(m, off, 64));
    float ex = expf(acc[0] - m) + expf(acc[1] - m) + expf(acc[2] - m) + expf(acc[3] - m);
    #pragma unroll
    for (int off = 1; off < 16; off <<= 1) ex += __shfl_xor(ex, off, 64);
    float ls = m + logf(ex);
    if (grp == 0) {
        float4 o = {acc[0] - ls, acc[1] - ls, acc[2] - ls, acc[3] - ls};
        ((float4*)(out + (size_t)node * OUT_DIM))[l16] = o;
    }
}

extern "C" void kernel_launch(void* const* d_in, const int* in_sizes, int n_in,
                              void* d_out, int out_size, void* d_ws, size_t ws_size,
                              hipStream_t stream) {
    const float* x  = (const float*)d_in[0];
    const int*   ei = (const int*)d_in[1];
    const float* W1 = (const float*)d_in[2];
    const float* b1 = (const float*)d_in[3];
    const float* W2 = (const float*)d_in[4];
    const float* b2 = (const float*)d_in[5];
    float* out = (float*)d_out;
    char* ws = (char*)d_ws;

    const int* srcp = ei;
    const int* dstp = ei + N_EDGES;

    // workspace layout (256-aligned)
    int*   coarseCursor = (int*)(ws);              // 196 int (doubles as coarseCnt)
    int*   offs   = (int*)(ws + 4096);             // 50000 int
    int*   cntg   = (int*)(ws + 262144);           // 50000 int
    float* dis    = (float*)(ws + 524288);         // 50000 f32
    short* Bp1    = (short*)(ws + 786432);         // 64 KB
    short* Bp2    = (short*)(ws + 851968);         // 32 KB
    int*   ssrc   = (int*)(ws + 917504);           // 196*8192*4 = 6.4 MB
    uint2* sedge  = (uint2*)(ws + 7340032);        // 196*8192*8 = 12.8 MB (dead after part2)
    short* aggx   = (short*)(ws + 7340032);        // 12.8 MB, overlays sedge (live after part2)
    short* xb     = (short*)(ws + 20185088);       // 12.8 MB
    short* h2     = (short*)(ws + 32985088);       // 6.4 MB bf16

    hipMemsetAsync(coarseCursor, 0, NPART * 4, stream);

    part1_pack_kernel<<<NPB + 24, 256, 0, stream>>>(srcp, dstp, coarseCursor, sedge,
                                                    W1, W2, Bp1, Bp2, N_EDGES);
    part2_kernel<<<NPART, 256, 0, stream>>>(sedge, coarseCursor, offs, cntg, dis, ssrc,
                                            x, xb, N_NODES);
    agg1_kernel<<<(N_NODES + 3) / 4, 256, 0, stream>>>(xb, ssrc, offs, cntg, dis, aggx, N_NODES);
    gemm_fused_kernel<<<(N_NODES + 63) / 64, 256, 0, stream>>>(aggx, Bp1, Bp2, b1, dis,
                                                               h2, N_NODES);
    agg2_kernel<<<(N_NODES + 3) / 4, 256, 0, stream>>>(h2, ssrc, offs, cntg, dis, b2, out, N_NODES);
}

// Round 10
// 201.119 us; speedup vs baseline: 11.2554x; 1.0252x over previous
//
#include <hip/hip_runtime.h>
#include <hip/hip_bf16.h>
#include <math.h>

#define N_NODES 50000
#define N_EDGES 800000
#define IN_DIM 128
#define HID_DIM 256
#define OUT_DIM 64
#define NPART 196            // ceil(N_NODES/256) coarse buckets
#define CAP 8192             // static per-bucket capacity (mean 4096, sigma 64)
#define CHUNK 2048           // edges per partition block
#define NPB ((N_EDGES + CHUNK - 1) / CHUNK)   // 391 partition blocks

typedef __attribute__((ext_vector_type(8))) short bf16x8;
typedef __attribute__((ext_vector_type(4))) short short4v;
typedef __attribute__((ext_vector_type(4))) float f32x4;

__device__ inline short f2bf(float f) {   // round-to-nearest-even bf16
    unsigned u = __float_as_uint(f);
    unsigned r = (u + 0x7fffu + ((u >> 16) & 1u)) >> 16;
    return (short)r;
}
__device__ inline float bf_lo(unsigned u) { return __uint_as_float(u << 16); }
__device__ inline float bf_hi(unsigned u) { return __uint_as_float(u & 0xffff0000u); }

// ---- blocks < NPB: pass-1 LDS-staged coarse partition by dst>>8 into static slots
// ---- blocks >= NPB: pack W1/W2 into MFMA B-frag bf16 order
__global__ __launch_bounds__(256) void part1_pack_kernel(const int* __restrict__ src,
                                                         const int* __restrict__ dst,
                                                         int* __restrict__ coarseCursor,
                                                         uint2* __restrict__ sedge,
                                                         const float* __restrict__ W1,
                                                         const float* __restrict__ W2,
                                                         short* __restrict__ Bp1,
                                                         short* __restrict__ Bp2, int E) {
    __shared__ int cnt_l[NPART];
    __shared__ int pref[NPART];
    __shared__ int gbase[NPART];
    __shared__ int ws4[4];
    __shared__ uint2 stage[CHUNK];
    int tid = threadIdx.x;
    if (blockIdx.x >= NPB) {
        // ---- pack path ----
        int idx = (blockIdx.x - NPB) * 256 + tid;
        const float* W; short* Bp; int N;
        const int T1 = (IN_DIM / 32) * (HID_DIM / 16) * 64;    // 4096
        const int T2 = (HID_DIM / 32) * (OUT_DIM / 16) * 64;   // 2048
        if (idx < T1) { W = W1; Bp = Bp1; N = HID_DIM; }
        else { idx -= T1; if (idx >= T2) return; W = W2; Bp = Bp2; N = OUT_DIM; }
        int lane = idx & 63;
        int frag = idx >> 6;
        int ntiles = N >> 4;
        int nt = frag % ntiles;
        int kt = frag / ntiles;
        int col = nt * 16 + (lane & 15);
        int krow = kt * 32 + (lane >> 4) * 8;
        bf16x8 pk;
        #pragma unroll
        for (int j = 0; j < 8; j++) pk[j] = f2bf(W[(size_t)(krow + j) * N + col]);
        *((bf16x8*)(Bp + (size_t)idx * 8)) = pk;
        return;
    }
    int e0 = blockIdx.x * CHUNK;
    if (tid < NPART) cnt_l[tid] = 0;
    __syncthreads();
    int es[CHUNK / 256], ed[CHUNK / 256];
    #pragma unroll
    for (int j = 0; j < CHUNK / 256; j++) {
        int e = e0 + j * 256 + tid;
        if (e < E) {
            es[j] = src[e]; ed[j] = dst[e];
            atomicAdd(&cnt_l[ed[j] >> 8], 1);
        } else ed[j] = -1;
    }
    __syncthreads();
    int lane = tid & 63, wid = tid >> 6;
    int v = (tid < NPART) ? cnt_l[tid] : 0;
    int s = v;
    #pragma unroll
    for (int off = 1; off < 64; off <<= 1) {
        int t = __shfl_up(s, off, 64);
        if (lane >= off) s += t;
    }
    if (lane == 63) ws4[wid] = s;
    __syncthreads();
    int wp = 0;
    #pragma unroll
    for (int w = 0; w < 4; w++) wp += (w < wid) ? ws4[w] : 0;
    int excl = s - v + wp;
    if (tid < NPART) pref[tid] = excl;
    __syncthreads();
    if (tid < NPART) cnt_l[tid] = excl;   // reuse as local cursor
    __syncthreads();
    #pragma unroll
    for (int j = 0; j < CHUNK / 256; j++) {
        if (ed[j] >= 0) {
            int c = ed[j] >> 8;
            int p = atomicAdd(&cnt_l[c], 1);
            stage[p] = make_uint2((unsigned)es[j], (unsigned)ed[j]);
        }
    }
    __syncthreads();
    if (tid < NPART) {
        int cl = cnt_l[tid] - pref[tid];
        gbase[tid] = (cl > 0) ? (tid * CAP + atomicAdd(&coarseCursor[tid], cl)) : 0;
    }
    __syncthreads();
    int total = (e0 + CHUNK <= E) ? CHUNK : (E - e0);
    for (int i = tid; i < total; i += 256) {
        uint2 ev = stage[i];
        int c = (int)(ev.y >> 8);
        sedge[gbase[c] + (i - pref[c])] = ev;
    }
}

// ---- pass 2 (one block per coarse bucket): local per-node count + scan -> offs/cnt/dis,
// ---- fine scatter with LDS cursors, then prep xb rows for this block's own 256 nodes.
__global__ __launch_bounds__(256) void part2_kernel(const uint2* __restrict__ sedge,
                                                    const int* __restrict__ coarseCnt,
                                                    int* __restrict__ offs,
                                                    int* __restrict__ cntg,
                                                    float* __restrict__ dis,
                                                    int* __restrict__ ssrc,
                                                    const float* __restrict__ x,
                                                    short* __restrict__ xb, int n) {
    __shared__ int kcnt[256];
    __shared__ int ws4[4];
    __shared__ float sdis[256];
    int b = blockIdx.x, tid = threadIdx.x;
    int base = b * CAP;
    int cb = coarseCnt[b];
    kcnt[tid] = 0;
    __syncthreads();
    for (int i = tid; i < cb; i += 256) {
        uint2 ev = sedge[base + i];
        atomicAdd(&kcnt[ev.y & 255], 1);
    }
    __syncthreads();
    int v = kcnt[tid];
    int lane = tid & 63, wid = tid >> 6;
    int s = v;
    #pragma unroll
    for (int off = 1; off < 64; off <<= 1) {
        int t = __shfl_up(s, off, 64);
        if (lane >= off) s += t;
    }
    if (lane == 63) ws4[wid] = s;
    __syncthreads();
    int wp = 0;
    #pragma unroll
    for (int w = 0; w < 4; w++) wp += (w < wid) ? ws4[w] : 0;
    int excl = s - v + wp;
    int node = b * 256 + tid;
    float dn = rsqrtf((float)v + 1.0f);   // +1 self-loop
    if (node < n) {
        offs[node] = base + excl;
        cntg[node] = v;
        dis[node] = dn;
    }
    sdis[tid] = dn;
    __syncthreads();
    kcnt[tid] = base + excl;              // becomes cursor
    __syncthreads();
    for (int i = tid; i < cb; i += 256) {
        uint2 ev = sedge[base + i];
        int pos = atomicAdd(&kcnt[ev.y & 255], 1);
        ssrc[pos] = (int)ev.x;
    }
    // prep: xb[nd,:] = bf16(x[nd,:] * dis[nd]) for this block's nodes, coalesced
    int rlane = tid & 31, rgrp = tid >> 5;
    for (int rb = 0; rb < 32; rb++) {
        int row = rb * 8 + rgrp;
        int nd = b * 256 + row;
        if (nd >= n) break;
        float d2 = sdis[row];
        float4 vv = ((const float4*)(x + (size_t)nd * IN_DIM))[rlane];
        short4v o = {f2bf(vv.x * d2), f2bf(vv.y * d2), f2bf(vv.z * d2), f2bf(vv.w * d2)};
        *((short4v*)(xb + (size_t)nd * IN_DIM + rlane * 4)) = o;
    }
}

// ------- layer-1 aggregate: wave per node, 8 groups x 8 lanes (32 B/lane/row).
// ------- Edge indices wave-loaded once; distributed via WAVE-UNIFORM __shfl rounds
// ------- (all 64 lanes active in every shuffle; out-of-range edges gated by 0/1 FMA).
// ------- ds_bpermute is undefined for inactive source lanes -> never shuffle divergently.
__global__ void agg1_kernel(const short* __restrict__ xb, const int* __restrict__ ssrc,
                            const int* __restrict__ offs, const int* __restrict__ cnt,
                            const float* __restrict__ dis, short* __restrict__ aggx, int n) {
    int lane = threadIdx.x & 63;
    int node = blockIdx.x * 4 + (threadIdx.x >> 6);
    if (node >= n) return;
    int grp = lane >> 3, l8 = lane & 7;
    int start = offs[node], c = cnt[node];
    int vidx = (lane < c) ? ssrc[start + lane] : 0;   // all indices in one coalesced load
    float acc[16] = {};
    int lim = (c < 64) ? c : 64;
    int rounds = (lim + 15) >> 4;                     // wave-uniform trip count
    for (int r = 0; r < rounds; r++) {
        int j0 = r * 16 + grp;
        int j1 = j0 + 8;
        int i0 = (j0 < 63) ? j0 : 63;                 // clamp: shuffle index always valid
        int i1 = (j1 < 63) ? j1 : 63;
        int s0 = __shfl(vidx, i0, 64);
        int s1 = __shfl(vidx, i1, 64);
        float g0 = (j0 < lim) ? 1.0f : 0.0f;
        float g1 = (j1 < lim) ? 1.0f : 0.0f;
        const uint4* r0 = (const uint4*)(xb + (size_t)s0 * IN_DIM + l8 * 16);
        const uint4* r1 = (const uint4*)(xb + (size_t)s1 * IN_DIM + l8 * 16);
        uint4 a0 = r0[0], a1 = r0[1];
        uint4 b0 = r1[0], b1 = r1[1];
        acc[0]  += g0 * bf_lo(a0.x); acc[1]  += g0 * bf_hi(a0.x);
        acc[2]  += g0 * bf_lo(a0.y); acc[3]  += g0 * bf_hi(a0.y);
        acc[4]  += g0 * bf_lo(a0.z); acc[5]  += g0 * bf_hi(a0.z);
        acc[6]  += g0 * bf_lo(a0.w); acc[7]  += g0 * bf_hi(a0.w);
        acc[8]  += g0 * bf_lo(a1.x); acc[9]  += g0 * bf_hi(a1.x);
        acc[10] += g0 * bf_lo(a1.y); acc[11] += g0 * bf_hi(a1.y);
        acc[12] += g0 * bf_lo(a1.z); acc[13] += g0 * bf_hi(a1.z);
        acc[14] += g0 * bf_lo(a1.w); acc[15] += g0 * bf_hi(a1.w);
        acc[0]  += g1 * bf_lo(b0.x); acc[1]  += g1 * bf_hi(b0.x);
        acc[2]  += g1 * bf_lo(b0.y); acc[3]  += g1 * bf_hi(b0.y);
        acc[4]  += g1 * bf_lo(b0.z); acc[5]  += g1 * bf_hi(b0.z);
        acc[6]  += g1 * bf_lo(b0.w); acc[7]  += g1 * bf_hi(b0.w);
        acc[8]  += g1 * bf_lo(b1.x); acc[9]  += g1 * bf_hi(b1.x);
        acc[10] += g1 * bf_lo(b1.y); acc[11] += g1 * bf_hi(b1.y);
        acc[12] += g1 * bf_lo(b1.z); acc[13] += g1 * bf_hi(b1.z);
        acc[14] += g1 * bf_lo(b1.w); acc[15] += g1 * bf_hi(b1.w);
    }
    // rare tail c > 64: per-lane global index loads, no shuffles
    for (int j = 64 + grp; j < c; j += 8) {
        int s0 = ssrc[start + j];
        const uint4* r0 = (const uint4*)(xb + (size_t)s0 * IN_DIM + l8 * 16);
        uint4 a0 = r0[0], a1 = r0[1];
        acc[0]  += bf_lo(a0.x); acc[1]  += bf_hi(a0.x); acc[2]  += bf_lo(a0.y); acc[3]  += bf_hi(a0.y);
        acc[4]  += bf_lo(a0.z); acc[5]  += bf_hi(a0.z); acc[6]  += bf_lo(a0.w); acc[7]  += bf_hi(a0.w);
        acc[8]  += bf_lo(a1.x); acc[9]  += bf_hi(a1.x); acc[10] += bf_lo(a1.y); acc[11] += bf_hi(a1.y);
        acc[12] += bf_lo(a1.z); acc[13] += bf_hi(a1.z); acc[14] += bf_lo(a1.w); acc[15] += bf_hi(a1.w);
    }
    #pragma unroll
    for (int k = 0; k < 16; k++) {
        acc[k] += __shfl_xor(acc[k], 8, 64);
        acc[k] += __shfl_xor(acc[k], 16, 64);
        acc[k] += __shfl_xor(acc[k], 32, 64);
    }
    if (grp == 0) {
        float dn = dis[node];
        const uint4* rs = (const uint4*)(xb + (size_t)node * IN_DIM + l8 * 16);
        uint4 a0 = rs[0], a1 = rs[1];
        acc[0]  += bf_lo(a0.x); acc[1]  += bf_hi(a0.x); acc[2]  += bf_lo(a0.y); acc[3]  += bf_hi(a0.y);
        acc[4]  += bf_lo(a0.z); acc[5]  += bf_hi(a0.z); acc[6]  += bf_lo(a0.w); acc[7]  += bf_hi(a0.w);
        acc[8]  += bf_lo(a1.x); acc[9]  += bf_hi(a1.x); acc[10] += bf_lo(a1.y); acc[11] += bf_hi(a1.y);
        acc[12] += bf_lo(a1.z); acc[13] += bf_hi(a1.z); acc[14] += bf_lo(a1.w); acc[15] += bf_hi(a1.w);
        bf16x8 o0, o1;
        #pragma unroll
        for (int k = 0; k < 8; k++) { o0[k] = f2bf(acc[k] * dn); o1[k] = f2bf(acc[k + 8] * dn); }
        short* dst0 = aggx + (size_t)node * IN_DIM + l8 * 16;
        *((bf16x8*)dst0) = o0;
        *((bf16x8*)(dst0 + 8)) = o1;
    }
}

// -------- fused MFMA GEMM: h2[r,:] = dis[r] * (relu(aggx[r,:]@W1 + b1) @ W2) ----------
#define H1_STRIDE 264
__global__ __launch_bounds__(256) void gemm_fused_kernel(const short* __restrict__ A,
                                                         const short* __restrict__ Bp1,
                                                         const short* __restrict__ Bp2,
                                                         const float* __restrict__ b1,
                                                         const float* __restrict__ dis,
                                                         short* __restrict__ h2, int M) {
    __shared__ short lds_h1[4][16][H1_STRIDE];
    int lane = threadIdx.x & 63;
    int w = threadIdx.x >> 6;
    int rowBase = blockIdx.x * 64 + w * 16;
    int arow = rowBase + (lane & 15);
    int kseg = lane >> 4;             // 0..3
    int col0 = lane & 15;

    // ---- phase A: h1 = relu(aggx @ W1 + b1), K=128, N=256 ----
    constexpr int NT1 = HID_DIM / 16;   // 16
    f32x4 acc1[NT1] = {};
    #pragma unroll
    for (int kt = 0; kt < IN_DIM / 32; kt++) {
        bf16x8 a = {};
        if (arow < M)
            a = *((const bf16x8*)(A + (size_t)arow * IN_DIM + kt * 32 + kseg * 8));
        #pragma unroll
        for (int nt = 0; nt < NT1; nt++) {
            bf16x8 b = *((const bf16x8*)(Bp1 + ((size_t)(kt * NT1 + nt) * 64 + lane) * 8));
            acc1[nt] = __builtin_amdgcn_mfma_f32_16x16x32_bf16(a, b, acc1[nt], 0, 0, 0);
        }
    }
    #pragma unroll
    for (int nt = 0; nt < NT1; nt++) {
        float bv = b1[nt * 16 + col0];
        #pragma unroll
        for (int i = 0; i < 4; i++) {
            float v = fmaxf(acc1[nt][i] + bv, 0.0f);
            lds_h1[w][kseg * 4 + i][nt * 16 + col0] = f2bf(v);
        }
    }
    // ---- phase B: h2 = (h1 @ W2) * dis, K=256, N=64; A-frags from own wave's LDS ----
    constexpr int NT2 = OUT_DIM / 16;   // 4
    f32x4 acc2[NT2] = {};
    #pragma unroll
    for (int kt = 0; kt < HID_DIM / 32; kt++) {
        bf16x8 a = *((const bf16x8*)&lds_h1[w][lane & 15][kt * 32 + kseg * 8]);
        #pragma unroll
        for (int nt = 0; nt < NT2; nt++) {
            bf16x8 b = *((const bf16x8*)(Bp2 + ((size_t)(kt * NT2 + nt) * 64 + lane) * 8));
            acc2[nt] = __builtin_amdgcn_mfma_f32_16x16x32_bf16(a, b, acc2[nt], 0, 0, 0);
        }
    }
    #pragma unroll
    for (int i = 0; i < 4; i++) {
        int r = rowBase + kseg * 4 + i;
        if (r >= M) continue;
        float sc = dis[r];
        #pragma unroll
        for (int nt = 0; nt < NT2; nt++)
            h2[(size_t)r * OUT_DIM + nt * 16 + col0] = f2bf(acc2[nt][i] * sc);
    }
}

// ------- layer-2 aggregate: wave per node, 8 groups x 8 lanes (16 B/lane/row),
// ------- wave-uniform shuffle rounds (gated FMA), + self-loop + bias + log_softmax ----
__global__ void agg2_kernel(const short* __restrict__ h2, const int* __restrict__ ssrc,
                            const int* __restrict__ offs, const int* __restrict__ cnt,
                            const float* __restrict__ dis, const float* __restrict__ b2,
                            float* __restrict__ out, int n) {
    int lane = threadIdx.x & 63;
    int node = blockIdx.x * 4 + (threadIdx.x >> 6);
    if (node >= n) return;
    int grp = lane >> 3, l8 = lane & 7;
    int start = offs[node], c = cnt[node];
    int vidx = (lane < c) ? ssrc[start + lane] : 0;
    float acc[8] = {};
    int lim = (c < 64) ? c : 64;
    int rounds = (lim + 15) >> 4;                     // wave-uniform
    for (int r = 0; r < rounds; r++) {
        int j0 = r * 16 + grp;
        int j1 = j0 + 8;
        int i0 = (j0 < 63) ? j0 : 63;
        int i1 = (j1 < 63) ? j1 : 63;
        int s0 = __shfl(vidx, i0, 64);
        int s1 = __shfl(vidx, i1, 64);
        float g0 = (j0 < lim) ? 1.0f : 0.0f;
        float g1 = (j1 < lim) ? 1.0f : 0.0f;
        uint4 p0 = *((const uint4*)(h2 + (size_t)s0 * OUT_DIM + l8 * 8));
        uint4 p1 = *((const uint4*)(h2 + (size_t)s1 * OUT_DIM + l8 * 8));
        acc[0] += g0 * bf_lo(p0.x); acc[1] += g0 * bf_hi(p0.x);
        acc[2] += g0 * bf_lo(p0.y); acc[3] += g0 * bf_hi(p0.y);
        acc[4] += g0 * bf_lo(p0.z); acc[5] += g0 * bf_hi(p0.z);
        acc[6] += g0 * bf_lo(p0.w); acc[7] += g0 * bf_hi(p0.w);
        acc[0] += g1 * bf_lo(p1.x); acc[1] += g1 * bf_hi(p1.x);
        acc[2] += g1 * bf_lo(p1.y); acc[3] += g1 * bf_hi(p1.y);
        acc[4] += g1 * bf_lo(p1.z); acc[5] += g1 * bf_hi(p1.z);
        acc[6] += g1 * bf_lo(p1.w); acc[7] += g1 * bf_hi(p1.w);
    }
    // rare tail c > 64
    for (int j = 64 + grp; j < c; j += 8) {
        int s0 = ssrc[start + j];
        uint4 p0 = *((const uint4*)(h2 + (size_t)s0 * OUT_DIM + l8 * 8));
        acc[0] += bf_lo(p0.x); acc[1] += bf_hi(p0.x); acc[2] += bf_lo(p0.y); acc[3] += bf_hi(p0.y);
        acc[4] += bf_lo(p0.z); acc[5] += bf_hi(p0.z); acc[6] += bf_lo(p0.w); acc[7] += bf_hi(p0.w);
    }
    #pragma unroll
    for (int k = 0; k < 8; k++) {
        acc[k] += __shfl_xor(acc[k], 8, 64);
        acc[k] += __shfl_xor(acc[k], 16, 64);
        acc[k] += __shfl_xor(acc[k], 32, 64);
    }
    // self-loop + dn scale + bias (cols l8*8 .. l8*8+7)
    float dn = dis[node];
    uint4 pv = *((const uint4*)(h2 + (size_t)node * OUT_DIM + l8 * 8));
    float4 bb0 = ((const float4*)b2)[l8 * 2];
    float4 bb1 = ((const float4*)b2)[l8 * 2 + 1];
    acc[0] = (acc[0] + bf_lo(pv.x)) * dn + bb0.x;
    acc[1] = (acc[1] + bf_hi(pv.x)) * dn + bb0.y;
    acc[2] = (acc[2] + bf_lo(pv.y)) * dn + bb0.z;
    acc[3] = (acc[3] + bf_hi(pv.y)) * dn + bb0.w;
    acc[4] = (acc[4] + bf_lo(pv.z)) * dn + bb1.x;
    acc[5] = (acc[5] + bf_hi(pv.z)) * dn + bb1.y;
    acc[6] = (acc[6] + bf_lo(pv.w)) * dn + bb1.z;
    acc[7] = (acc[7] + bf_hi(pv.w)) * dn + bb1.w;
    // log_softmax over 64 cols (8 l8-lanes x 8 regs)
    float m = acc[0];
    #pragma unroll
    for (int k = 1; k < 8; k++) m = fmaxf(m, acc[k]);
    #pragma unroll
    for (int off = 1; off < 8; off <<= 1) m = fmaxf(m, __shfl_xor(m, off, 64));
    float ex = 0.0f;
    #pragma unroll
    for (int k = 0; k < 8; k++) ex += expf(acc[k] - m);
    #pragma unroll
    for (int off = 1; off < 8; off <<= 1) ex += __shfl_xor(ex, off, 64);
    float ls = m + logf(ex);
    if (grp == 0) {
        float4 o0 = {acc[0] - ls, acc[1] - ls, acc[2] - ls, acc[3] - ls};
        float4 o1 = {acc[4] - ls, acc[5] - ls, acc[6] - ls, acc[7] - ls};
        ((float4*)(out + (size_t)node * OUT_DIM))[l8 * 2] = o0;
        ((float4*)(out + (size_t)node * OUT_DIM))[l8 * 2 + 1] = o1;
    }
}

extern "C" void kernel_launch(void* const* d_in, const int* in_sizes, int n_in,
                              void* d_out, int out_size, void* d_ws, size_t ws_size,
                              hipStream_t stream) {
    const float* x  = (const float*)d_in[0];
    const int*   ei = (const int*)d_in[1];
    const float* W1 = (const float*)d_in[2];
    const float* b1 = (const float*)d_in[3];
    const float* W2 = (const float*)d_in[4];
    const float* b2 = (const float*)d_in[5];
    float* out = (float*)d_out;
    char* ws = (char*)d_ws;

    const int* srcp = ei;
    const int* dstp = ei + N_EDGES;

    // workspace layout (256-aligned)
    int*   coarseCursor = (int*)(ws);              // 196 int (doubles as coarseCnt)
    int*   offs   = (int*)(ws + 4096);             // 50000 int
    int*   cntg   = (int*)(ws + 262144);           // 50000 int
    float* dis    = (float*)(ws + 524288);         // 50000 f32
    short* Bp1    = (short*)(ws + 786432);         // 64 KB
    short* Bp2    = (short*)(ws + 851968);         // 32 KB
    int*   ssrc   = (int*)(ws + 917504);           // 196*8192*4 = 6.4 MB
    uint2* sedge  = (uint2*)(ws + 7340032);        // 196*8192*8 = 12.8 MB (dead after part2)
    short* aggx   = (short*)(ws + 7340032);        // 12.8 MB, overlays sedge (live after part2)
    short* xb     = (short*)(ws + 20185088);       // 12.8 MB
    short* h2     = (short*)(ws + 32985088);       // 6.4 MB bf16

    hipMemsetAsync(coarseCursor, 0, NPART * 4, stream);

    part1_pack_kernel<<<NPB + 24, 256, 0, stream>>>(srcp, dstp, coarseCursor, sedge,
                                                    W1, W2, Bp1, Bp2, N_EDGES);
    part2_kernel<<<NPART, 256, 0, stream>>>(sedge, coarseCursor, offs, cntg, dis, ssrc,
                                            x, xb, N_NODES);
    agg1_kernel<<<(N_NODES + 3) / 4, 256, 0, stream>>>(xb, ssrc, offs, cntg, dis, aggx, N_NODES);
    gemm_fused_kernel<<<(N_NODES + 63) / 64, 256, 0, stream>>>(aggx, Bp1, Bp2, b1, dis,
                                                               h2, N_NODES);
    agg2_kernel<<<(N_NODES + 3) / 4, 256, 0, stream>>>(h2, ssrc, offs, cntg, dis, b2, out, N_NODES);
}